// Round 5
// baseline (3212.986 us; speedup 1.0000x reference)
//
#include <hip/hip_runtime.h>

// ---------------- problem dims ----------------
// B=1, S=1024, C=2048, H=32, D=64, HKV=8, R=16, FF=5632, Q_BIT=4 (qmax=7)

// ---------------- ws layout (float offsets) ----------------
#define WS_XN1   0L            // also QHG/QLG (bf16) after qkv; also CAND during quantile
#define WS_Q     2097152L
#define WS_KB    4194304L
#define WS_VB    4718592L
#define WS_OB    5242880L
#define WS_XMED  7340032L      // also KHG/KLG/VTH/VTL (bf16) during attention
#define WS_XN2   9437184L
#define WS_PROBS 11534336L     // 33554432 floats
// ---- phase A aliases (inside probs; dead before score writes probs) ----
#define PA        WS_PROBS
#define A_WQ      (PA + 0L)
#define A_WK      (PA + 2097152L)
#define A_WV      (PA + 2621440L)
#define A_XN1H    (PA + 3145728L)
#define A_XN1L    (PA + 4194304L)
#define A_XAQH    (PA + 5242880L)
#define A_XAQL    (PA + 5259264L)
#define A_XAKH    (PA + 5275648L)
#define A_XAKL    (PA + 5292032L)
#define A_XAVH    (PA + 5308416L)
#define A_XAVL    (PA + 5324800L)
#define A_LBTQ    (PA + 5341184L)
#define A_LBTK    (PA + 5373952L)
#define A_LBTV    (PA + 5382144L)
// ---- attention bf16 aliases (outside probs) ----
#define AT_QHG    (WS_XN1 + 0L)        // 1024x2048 bf16
#define AT_QLG    (WS_XN1 + 1048576L)
#define AT_KHG    (WS_XMED + 0L)       // 1024x512 bf16
#define AT_KLG    (WS_XMED + 262144L)
#define AT_VTH    (WS_XMED + 524288L)  // 8x64x1024 bf16
#define AT_VTL    (WS_XMED + 786432L)
#define CAND_OFF  WS_XN1               // quantile candidates (<=2M floats)
#define CAP_CAND  2097152u
// ---- phase B aliases (inside probs; written only after quantile) ----
#define B_WO      (PA + 0L)
#define B_OH      (PA + 2097152L)
#define B_OL      (PA + 3145728L)
#define B_XAOH    (PA + 4194304L)
#define B_XAOL    (PA + 4210688L)
#define B_LBTO    (PA + 4227072L)
#define B_WG      (PA + 4300800L)
#define B_WU      (PA + 10067968L)
#define B_XN2H    (PA + 15835136L)
#define B_XN2L    (PA + 16883712L)
#define B_XAGH    (PA + 17932288L)
#define B_XAGL    (PA + 17948672L)
#define B_XAUH    (PA + 17965056L)
#define B_XAUL    (PA + 17981440L)
#define B_LBTG    (PA + 17997824L)
#define B_LBTU    (PA + 18087936L)
#define B_GATE    (PA + 18178048L)
#define B_UP      (PA + 23945216L)
#define B_HAD     (PA + 4300800L)      // WG slot
#define B_WD      (PA + 10067968L)     // WU slot
#define B_HADH    (PA + 0L)            // WO+OH slots
#define B_HADL    (PA + 18178048L)     // GATE slot
#define B_XADH    (PA + 15835136L)
#define B_XADL    (PA + 15851520L)
#define B_LBTD    (PA + 15867904L)
// ---- small stuff ----
#define WS_SMALL 45088768L
#define CM_X     (WS_SMALL + 0L)
#define CM_XN1   (WS_SMALL + 2048L)
#define CM_Qb    (WS_SMALL + 4096L)
#define CM_Kb    (WS_SMALL + 4160L)
#define CM_Vb    (WS_SMALL + 4224L)
#define CM_Ob    (WS_SMALL + 4288L)
#define CM_XM    (WS_SMALL + 6336L)
#define CM_XN2b  (WS_SMALL + 8384L)
#define CM_GATE  (WS_SMALL + 10432L)
#define CM_FN    (WS_SMALL + 16064L)
#define CM_UPb   (WS_SMALL + 21696L)
#define CM_HAD   (WS_SMALL + 27328L)
#define CM_TOTAL 32960
#define WS_IDX   (WS_SMALL + 32960L)
#define WS_HIST  (WS_IDX + 64L)
#define WS_SEL   (WS_HIST + 4096L)
#define WS_RES   (WS_SEL + 8L)

// ---------------- out layout (float offsets) ----------------
#define O_XOUT  0L
#define O_XIDX  2097152L
#define O_XSC   2097172L
#define O_XN1S  2099220L
#define O_QS    2101268L
#define O_KS    2101332L
#define O_VS    2101396L
#define O_ATHR  2101460L
#define O_OS    2101461L
#define O_XMIDX 2103509L
#define O_XMS   2103529L
#define O_XN2S  2105577L
#define O_GATES 2107625L
#define O_UPS   2113257L
#define O_FNS   2118889L
#define O_HADS  2124521L

typedef float  floatx4 __attribute__((ext_vector_type(4)));
typedef short  shortx8 __attribute__((ext_vector_type(8)));

static __device__ __forceinline__ unsigned short f2bf(float f) {
    unsigned u = __float_as_uint(f);
    return (unsigned short)((u + 0x7FFFu + ((u >> 16) & 1u)) >> 16);
}
static __device__ __forceinline__ float bf2f(unsigned short b) {
    return __uint_as_float(((unsigned)b) << 16);
}
static __device__ __forceinline__ void gload_lds16(const void* g, void* l) {
    __builtin_amdgcn_global_load_lds(
        (const __attribute__((address_space(1))) unsigned int*)g,
        (__attribute__((address_space(3))) unsigned int*)l, 16, 0, 0);
}
static __device__ __forceinline__ void cvt8(const float4 a, const float4 b,
                                            shortx8& h8, shortx8& l8) {
    float v[8] = {a.x, a.y, a.z, a.w, b.x, b.y, b.z, b.w};
#pragma unroll
    for (int i = 0; i < 8; i++) {
        unsigned short h = f2bf(v[i]);
        h8[i] = (short)h;
        l8[i] = (short)f2bf(v[i] - bf2f(h));
    }
}

// ---------------- small utility kernels ----------------
__global__ void zero_kernel(unsigned* __restrict__ p, int n) {
    int i = blockIdx.x * 256 + threadIdx.x;
    if (i < n) p[i] = 0u;
}

__global__ __launch_bounds__(256) void rmsnorm_kernel(const float* __restrict__ x,
                                                      const float* __restrict__ w,
                                                      float* __restrict__ out) {
    const int row = blockIdx.x;
    const int tid = threadIdx.x;
    const float* xr = x + row * 2048;
    float s = 0.f;
    for (int i = tid; i < 2048; i += 256) { float v = xr[i]; s += v * v; }
    __shared__ float red[256];
    red[tid] = s; __syncthreads();
    for (int off = 128; off; off >>= 1) { if (tid < off) red[tid] += red[tid + off]; __syncthreads(); }
    const float rstd = 1.0f / sqrtf(red[0] / 2048.0f + 1e-5f);
    float* orow = out + row * 2048;
    for (int i = tid; i < 2048; i += 256) orow[i] = xr[i] * rstd * w[i];
}

__global__ void colabsmax_kernel(const float* __restrict__ in, int M, int N,
                                 unsigned* __restrict__ outb) {
    const int c = blockIdx.x * 256 + threadIdx.x;
    if (c >= N) return;
    float loc = 0.f;
    for (int r = blockIdx.y; r < M; r += gridDim.y)
        loc = fmaxf(loc, fabsf(in[(long)r * N + c]));
    atomicMax(outb + c, __float_as_uint(loc));
}

__global__ __launch_bounds__(256) void scale_fin_all_kernel(const unsigned* __restrict__ cm,
                                                            float* __restrict__ OUT) {
    int i = blockIdx.x * 256 + threadIdx.x;
    const int  n[10]  = {2048, 64, 64, 64, 2048, 2048, 5632, 5632, 5632, 5632};
    const int  co[10] = {2048, 4096, 4160, 4224, 4288, 8384, 10432, 16064, 21696, 27328};
    const long oo[10] = {O_XN1S, O_QS, O_KS, O_VS, O_OS, O_XN2S, O_GATES, O_FNS, O_UPS, O_HADS};
#pragma unroll
    for (int s = 0; s < 10; s++) {
        if (i < n[s]) { OUT[oo[s] + i] = __uint_as_float(cm[co[s] + i]) / 7.0f + 1e-8f; return; }
        i -= n[s];
    }
}

__global__ __launch_bounds__(256) void topk20_kernel(const unsigned* __restrict__ cmaxbits,
                                                     float* __restrict__ out_idx_f,
                                                     int* __restrict__ out_idx_i) {
    __shared__ float vals[2048];
    __shared__ float rv[256];
    __shared__ int   ri[256];
    const int tid = threadIdx.x;
    for (int i = tid; i < 2048; i += 256) vals[i] = __uint_as_float(cmaxbits[i]);
    __syncthreads();
    for (int t = 0; t < 20; t++) {
        float bv = -1.f; int bi = 1 << 30;
        for (int i = tid; i < 2048; i += 256) {
            float v = vals[i];
            if (v > bv) { bv = v; bi = i; }
        }
        rv[tid] = bv; ri[tid] = bi; __syncthreads();
        for (int off = 128; off; off >>= 1) {
            if (tid < off) {
                float v2 = rv[tid + off]; int i2 = ri[tid + off];
                if (v2 > rv[tid] || (v2 == rv[tid] && i2 < ri[tid])) { rv[tid] = v2; ri[tid] = i2; }
            }
            __syncthreads();
        }
        if (tid == 0) { out_idx_f[t] = (float)ri[0]; out_idx_i[t] = ri[0]; vals[ri[0]] = -1.f; }
        __syncthreads();
    }
}

__global__ void packscale_kernel(const unsigned* __restrict__ cmaxbits,
                                 const int* __restrict__ idx, float* __restrict__ out, int n) {
    const int c = blockIdx.x * 256 + threadIdx.x;
    if (c >= n) return;
    bool outl = false;
    for (int t = 0; t < 20; t++) outl |= (idx[t] == c);
    const float m = __uint_as_float(cmaxbits[c]);
    out[c] = outl ? 1e-8f : (m / 7.0f + 1e-8f);
}

// up to 3 LoRA xa projections in one pass over A
__global__ __launch_bounds__(256) void lora_xa_multi_kernel(
    const float* __restrict__ A, int K, int nset,
    const float* __restrict__ la0, unsigned short* __restrict__ xh0, unsigned short* __restrict__ xl0,
    const float* __restrict__ la1, unsigned short* __restrict__ xh1, unsigned short* __restrict__ xl1,
    const float* __restrict__ la2, unsigned short* __restrict__ xh2, unsigned short* __restrict__ xl2) {
    const int m = blockIdx.x;
    const int tid = threadIdx.x;
    const int r = tid & 15, g = tid >> 4;
    float s0 = 0.f, s1 = 0.f, s2 = 0.f;
    const float* Am = A + (long)m * K;
    for (int k = g; k < K; k += 16) {
        const float a = Am[k];
        s0 += a * la0[k * 16 + r];
        if (nset > 1) s1 += a * la1[k * 16 + r];
        if (nset > 2) s2 += a * la2[k * 16 + r];
    }
    __shared__ float red[768];
    red[tid] = s0; red[256 + tid] = s1; red[512 + tid] = s2; __syncthreads();
    for (int off = 128; off >= 16; off >>= 1) {
        if (tid < off) {
            red[tid] += red[tid + off];
            red[256 + tid] += red[256 + tid + off];
            red[512 + tid] += red[512 + tid + off];
        }
        __syncthreads();
    }
    if (tid < 16) {
        float v = red[tid]; unsigned short h = f2bf(v);
        xh0[m * 32 + tid] = h; xl0[m * 32 + tid] = f2bf(v - bf2f(h));
        if (nset > 1) { v = red[256 + tid]; h = f2bf(v); xh1[m * 32 + tid] = h; xl1[m * 32 + tid] = f2bf(v - bf2f(h)); }
        if (nset > 2) { v = red[512 + tid]; h = f2bf(v); xh2[m * 32 + tid] = h; xl2[m * 32 + tid] = f2bf(v - bf2f(h)); }
    } else if (tid < 32) {
        xh0[m * 32 + tid] = 0; xl0[m * 32 + tid] = 0;
        if (nset > 1) { xh1[m * 32 + tid] = 0; xl1[m * 32 + tid] = 0; }
        if (nset > 2) { xh2[m * 32 + tid] = 0; xl2[m * 32 + tid] = 0; }
    }
}

__global__ void hilo_kernel(const float* __restrict__ in, unsigned short* __restrict__ hi,
                            unsigned short* __restrict__ lo, long n4) {
    const long i = (long)blockIdx.x * 256 + threadIdx.x;
    if (i >= n4) return;
    const float4 v = *(const float4*)(in + i * 4);
    ushort4 h, l;
    h.x = f2bf(v.x); l.x = f2bf(v.x - bf2f(h.x));
    h.y = f2bf(v.y); l.y = f2bf(v.y - bf2f(h.y));
    h.z = f2bf(v.z); l.z = f2bf(v.z - bf2f(h.z));
    h.w = f2bf(v.w); l.w = f2bf(v.w - bf2f(h.w));
    *(ushort4*)(hi + i * 4) = h;
    *(ushort4*)(lo + i * 4) = l;
}

__global__ void w2bf_kernel(const int* __restrict__ wi, unsigned short* __restrict__ out, long n4) {
    const long i = (long)blockIdx.x * 256 + threadIdx.x;
    if (i >= n4) return;
    const int4 w = *(const int4*)(wi + i * 4);
    ushort4 o;
    o.x = (unsigned short)(__float_as_uint((float)w.x) >> 16);
    o.y = (unsigned short)(__float_as_uint((float)w.y) >> 16);
    o.z = (unsigned short)(__float_as_uint((float)w.z) >> 16);
    o.w = (unsigned short)(__float_as_uint((float)w.w) >> 16);
    *(ushort4*)(out + i * 4) = o;
}

__global__ void lbt_kernel(const float* __restrict__ lb, const float* __restrict__ sc,
                           unsigned short* __restrict__ out, int N) {
    const int n = blockIdx.x * 256 + threadIdx.x;
    if (n >= N) return;
    const float inv = 1.0f / sc[n];
    for (int r = 0; r < 16; r++) out[n * 32 + r] = f2bf(lb[r * N + n] * inv);
    for (int r = 16; r < 32; r++) out[n * 32 + r] = 0;
}

// rope in-place + emit bf16 hi/lo copies
__global__ void rope_kernel(float* __restrict__ x, unsigned short* __restrict__ xh,
                            unsigned short* __restrict__ xl,
                            const float* __restrict__ cs, const float* __restrict__ sn, int nh) {
    const int idx = blockIdx.x * 256 + threadIdx.x;
    const int tot = 1024 * nh * 32;
    if (idx >= tot) return;
    const int d = idx & 31;
    const int h = (idx >> 5) % nh;
    const int s = (idx >> 5) / nh;
    const long e = (long)s * (nh * 64) + h * 64 + d;
    const float x1 = x[e], x2 = x[e + 32];
    const float c1 = cs[s * 64 + d],      s1 = sn[s * 64 + d];
    const float c2 = cs[s * 64 + d + 32], s2 = sn[s * 64 + d + 32];
    const float v1 = x1 * c1 - x2 * s1;
    const float v2 = x2 * c2 + x1 * s2;
    x[e] = v1; x[e + 32] = v2;
    unsigned short h1 = f2bf(v1), h2 = f2bf(v2);
    xh[e] = h1;      xl[e] = f2bf(v1 - bf2f(h1));
    xh[e + 32] = h2; xl[e + 32] = f2bf(v2 - bf2f(h2));
}

// V -> VT (bf16 hi/lo, [kvh][64 d][1024 s]) + per-d abs-max
__global__ __launch_bounds__(256) void vtrans_kernel(const float* __restrict__ V,
                                                     unsigned short* __restrict__ vth,
                                                     unsigned short* __restrict__ vtl,
                                                     unsigned* __restrict__ cmv) {
    __shared__ float T[64][65];
    __shared__ unsigned vmax[64];
    const int st = blockIdx.x, h = blockIdx.y, t = threadIdx.x;
    if (t < 64) vmax[t] = 0u;
    const int r = t >> 2, cb = (t & 3) * 16;
    const float* src = V + (size_t)(st * 64 + r) * 512 + h * 64 + cb;
#pragma unroll
    for (int i = 0; i < 4; i++) {
        const float4 v = *(const float4*)(src + i * 4);
        T[r][cb + i * 4 + 0] = v.x; T[r][cb + i * 4 + 1] = v.y;
        T[r][cb + i * 4 + 2] = v.z; T[r][cb + i * 4 + 3] = v.w;
    }
    __syncthreads();
    const int dd = t >> 2, sb = (t & 3) * 16;
    shortx8 th0, th1, tl0, tl1;
    float mx = 0.f;
#pragma unroll
    for (int i = 0; i < 16; i++) {
        const float f = T[sb + i][dd];
        mx = fmaxf(mx, fabsf(f));
        const unsigned short hh = f2bf(f);
        const unsigned short ll = f2bf(f - bf2f(hh));
        if (i < 8) { th0[i] = (short)hh; tl0[i] = (short)ll; }
        else       { th1[i - 8] = (short)hh; tl1[i - 8] = (short)ll; }
    }
    atomicMax(&vmax[dd], __float_as_uint(mx));
    const size_t off = (size_t)(h * 64 + dd) * 1024 + st * 64 + sb;
    *(shortx8*)&vth[off] = th0; *(shortx8*)&vth[off + 8] = th1;
    *(shortx8*)&vtl[off] = tl0; *(shortx8*)&vtl[off + 8] = tl1;
    __syncthreads();
    if (t < 64) atomicMax(cmv + t, vmax[t]);
}

// gate/up -> had + 4 column abs-maxes
__global__ __launch_bounds__(256) void hadfuse_kernel(const float* __restrict__ gate,
                                                      const float* __restrict__ up,
                                                      float* __restrict__ had,
                                                      unsigned* __restrict__ cmg, unsigned* __restrict__ cmf,
                                                      unsigned* __restrict__ cmu, unsigned* __restrict__ cmh) {
    const int c = blockIdx.x * 256 + threadIdx.x;
    if (c >= 5632) return;
    float mg = 0.f, mf = 0.f, mu = 0.f, mh = 0.f;
    for (int r = blockIdx.y; r < 1024; r += gridDim.y) {
        const float g = gate[(long)r * 5632 + c];
        const float u = up[(long)r * 5632 + c];
        const float fn = g / (1.f + expf(-g));
        const float hv = u * fn;
        had[(long)r * 5632 + c] = hv;
        mg = fmaxf(mg, fabsf(g)); mf = fmaxf(mf, fabsf(fn));
        mu = fmaxf(mu, fabsf(u)); mh = fmaxf(mh, fabsf(hv));
    }
    atomicMax(cmg + c, __float_as_uint(mg));
    atomicMax(cmf + c, __float_as_uint(mf));
    atomicMax(cmu + c, __float_as_uint(mu));
    atomicMax(cmh + c, __float_as_uint(mh));
}

// ---------------- MFMA GEMM with split-K ----------------
struct Seg {
    const unsigned short *W, *xh, *xl, *lbt;
    const float *sc, *b, *res;
    float *C;
    int N;
    int bx0;
};

__global__ __launch_bounds__(256) void gemm_mfma3_kernel(
    const unsigned short* __restrict__ Ah, const unsigned short* __restrict__ Al,
    int K, int Kc, int KS, int c1, int c2, Seg s0, Seg s1, Seg s2)
{
    __shared__ unsigned short lds[2][3][4096];   // dbuf x {AH, AL, B} x 8KB
    const int tid  = threadIdx.x;
    const int wave = tid >> 6, lane = tid & 63;
    const Seg s = (blockIdx.x < c1) ? s0 : (blockIdx.x < c2) ? s1 : s2;
    const int bn = (blockIdx.x - s.bx0) * 128;
    const int bm = blockIdx.y * 128;
    const int z  = blockIdx.z;
    const int wm = (wave >> 1) * 64, wn = (wave & 1) * 64;
    const int l15 = lane & 15, l4 = lane >> 4;
    const int qe = (l4 ^ ((l15 >> 1) & 3)) * 8;
    const int lrow = lane >> 2;
    const int csrc = (lane & 3) ^ ((lane >> 3) & 3);
    const size_t strideMain = (size_t)K * 2;
    const int iters = Kc >> 5;
    const int nsteps = iters + (z == 0 ? 1 : 0);

    floatx4 acc[4][4];
#pragma unroll
    for (int i = 0; i < 4; i++)
#pragma unroll
        for (int j = 0; j < 4; j++) acc[i][j] = (floatx4){0.f, 0.f, 0.f, 0.f};

    auto load3 = [&](int it, int buf) {
        const char *pAh, *pAl, *pB; size_t stA, stB, kb;
        if (it < iters) {
            pAh = (const char*)Ah; pAl = (const char*)Al; pB = (const char*)s.W;
            stA = strideMain; stB = strideMain; kb = (size_t)(z * Kc + it * 32) * 2;
        } else {
            pAh = (const char*)s.xh; pAl = (const char*)s.xl; pB = (const char*)s.lbt;
            stA = 64; stB = 64; kb = 0;
        }
#pragma unroll
        for (int issue = 0; issue < 2; issue++) {
            const int rt = wave * 32 + issue * 16 + lrow;
            const size_t co = kb + (size_t)csrc * 16;
            unsigned short* d0 = &lds[buf][0][(wave * 32 + issue * 16) * 32];
            unsigned short* d1 = &lds[buf][1][(wave * 32 + issue * 16) * 32];
            unsigned short* d2 = &lds[buf][2][(wave * 32 + issue * 16) * 32];
            gload_lds16(pAh + (size_t)(bm + rt) * stA + co, d0);
            gload_lds16(pAl + (size_t)(bm + rt) * stA + co, d1);
            gload_lds16(pB  + (size_t)(bn + rt) * stB + co, d2);
        }
    };

    load3(0, 0);
    for (int it = 0; it < nsteps; it++) {
        const int cur = it & 1;
        __syncthreads();
        if (it + 1 < nsteps) load3(it + 1, cur ^ 1);
        const unsigned short* tAh = lds[cur][0];
        const unsigned short* tAl = lds[cur][1];
        const unsigned short* tB  = lds[cur][2];
        shortx8 afh[4], afl[4], bfr[4];
#pragma unroll
        for (int i = 0; i < 4; i++) {
            afh[i] = *(const shortx8*)&tAh[(wm + i * 16 + l15) * 32 + qe];
            afl[i] = *(const shortx8*)&tAl[(wm + i * 16 + l15) * 32 + qe];
            bfr[i] = *(const shortx8*)&tB [(wn + i * 16 + l15) * 32 + qe];
        }
#pragma unroll
        for (int i = 0; i < 4; i++)
#pragma unroll
            for (int j = 0; j < 4; j++) {
                acc[i][j] = __builtin_amdgcn_mfma_f32_16x16x32_bf16(afh[i], bfr[j], acc[i][j], 0, 0, 0);
                acc[i][j] = __builtin_amdgcn_mfma_f32_16x16x32_bf16(afl[i], bfr[j], acc[i][j], 0, 0, 0);
            }
    }

#pragma unroll
    for (int j = 0; j < 4; j++) {
        const int n = bn + wn + j * 16 + l15;
        const float scn = s.sc[n];
        const float bsn = (z == 0) ? s.b[n] : 0.f;
#pragma unroll
        for (int i = 0; i < 4; i++) {
            const int m0 = bm + wm + i * 16 + l4 * 4;
#pragma unroll
            for (int r = 0; r < 4; r++) {
                const int m = m0 + r;
                float v = acc[i][j][r] * scn + bsn;
                if (z == 0 && s.res) v += s.res[(size_t)m * s.N + n];
                if (KS == 1) s.C[(size_t)m * s.N + n] = v;
                else atomicAdd(&s.C[(size_t)m * s.N + n], v);
            }
        }
    }
}

// ---------------- attention: MFMA score (lower-triangle 128x128 tiles) ----------------
__global__ __launch_bounds__(256) void score_mfma_kernel(
    const unsigned short* __restrict__ QH, const unsigned short* __restrict__ QL,
    const unsigned short* __restrict__ KH, const unsigned short* __restrict__ KL,
    float* __restrict__ probs)
{
    __shared__ unsigned short q_h[4096], q_l[4096], k_h[4096], k_l[4096];
    const int tid = threadIdx.x, wave = tid >> 6, lane = tid & 63;
    const int t = blockIdx.x, h = blockIdx.y;
    int by = 0;
    while ((by + 1) * (by + 2) / 2 <= t) by++;
    const int bx = t - by * (by + 1) / 2;
    const int wm = (wave >> 1) * 64, wn = (wave & 1) * 64;
    const int l15 = lane & 15, l4 = lane >> 4;
    const int qe = (l4 ^ ((l15 >> 1) & 3)) * 8;
    const int lrow = lane >> 2;
    const int csrc = (lane & 3) ^ ((lane >> 3) & 3);

    floatx4 acc[4][4];
#pragma unroll
    for (int i = 0; i < 4; i++)
#pragma unroll
        for (int j = 0; j < 4; j++) acc[i][j] = (floatx4){0.f, 0.f, 0.f, 0.f};

    for (int s = 0; s < 2; s++) {
        __syncthreads();
#pragma unroll
        for (int issue = 0; issue < 2; issue++) {
            const int rq = by * 128 + wave * 32 + issue * 16 + lrow;
            const int rk = bx * 128 + wave * 32 + issue * 16 + lrow;
            const size_t coq = ((size_t)rq * 2048 + h * 64 + s * 32) * 2 + (size_t)csrc * 16;
            const size_t cok = ((size_t)rk * 512 + (h >> 2) * 64 + s * 32) * 2 + (size_t)csrc * 16;
            const int db = (wave * 32 + issue * 16) * 32;
            gload_lds16((const char*)QH + coq, &q_h[db]);
            gload_lds16((const char*)QL + coq, &q_l[db]);
            gload_lds16((const char*)KH + cok, &k_h[db]);
            gload_lds16((const char*)KL + cok, &k_l[db]);
        }
        __syncthreads();
        shortx8 ah[4], al[4], bh[4], bl[4];
#pragma unroll
        for (int i = 0; i < 4; i++) {
            ah[i] = *(const shortx8*)&q_h[(wm + i * 16 + l15) * 32 + qe];
            al[i] = *(const shortx8*)&q_l[(wm + i * 16 + l15) * 32 + qe];
            bh[i] = *(const shortx8*)&k_h[(wn + i * 16 + l15) * 32 + qe];
            bl[i] = *(const shortx8*)&k_l[(wn + i * 16 + l15) * 32 + qe];
        }
#pragma unroll
        for (int i = 0; i < 4; i++)
#pragma unroll
            for (int j = 0; j < 4; j++) {
                acc[i][j] = __builtin_amdgcn_mfma_f32_16x16x32_bf16(ah[i], bh[j], acc[i][j], 0, 0, 0);
                acc[i][j] = __builtin_amdgcn_mfma_f32_16x16x32_bf16(al[i], bh[j], acc[i][j], 0, 0, 0);
                acc[i][j] = __builtin_amdgcn_mfma_f32_16x16x32_bf16(ah[i], bl[j], acc[i][j], 0, 0, 0);
            }
    }
#pragma unroll
    for (int j = 0; j < 4; j++) {
        const int col = bx * 128 + wn + j * 16 + l15;
#pragma unroll
        for (int i = 0; i < 4; i++) {
#pragma unroll
            for (int r = 0; r < 4; r++) {
                const int row = by * 128 + wm + i * 16 + l4 * 4 + r;
                probs[((size_t)(h * 1024) + row) * 1024 + col] = acc[i][j][r] * 0.125f;
            }
        }
    }
}

__global__ __launch_bounds__(256) void softmax_kernel(float* __restrict__ probs) {
    const int row = blockIdx.x;
    const int qi = row & 1023;
    float* p = probs + (long)row * 1024;
    const int tid = threadIdx.x;
    __shared__ float red[256];
    float m = -3.4e38f;
    for (int i = tid; i <= qi; i += 256) m = fmaxf(m, p[i]);
    red[tid] = m; __syncthreads();
    for (int off = 128; off; off >>= 1) { if (tid < off) red[tid] = fmaxf(red[tid], red[tid + off]); __syncthreads(); }
    m = red[0]; __syncthreads();
    float s = 0.f;
    for (int i = tid; i <= qi; i += 256) { float e = expf(p[i] - m); p[i] = e; s += e; }
    red[tid] = s; __syncthreads();
    for (int off = 128; off; off >>= 1) { if (tid < off) red[tid] += red[tid + off]; __syncthreads(); }
    const float inv = 1.f / red[0];
    for (int i = tid; i < 1024; i += 256) p[i] = (i <= qi) ? p[i] * inv : 0.f;
}

// ---------------- attention: MFMA AV (64-row q tiles) ----------------
__global__ __launch_bounds__(256) void av_mfma_kernel(
    const float* __restrict__ probs,
    const unsigned short* __restrict__ VTH, const unsigned short* __restrict__ VTL,
    float* __restrict__ obuf)
{
    __shared__ unsigned short p_h[4096], p_l[4096];   // [2 sub][64][32]
    __shared__ unsigned short v_h[4096], v_l[4096];
    const int tid = threadIdx.x, wave = tid >> 6, lane = tid & 63;
    const int qt = blockIdx.x, h = blockIdx.y;
    const int wm = (wave >> 1) * 32, wn = (wave & 1) * 32;
    const int l15 = lane & 15, l4 = lane >> 4;
    const int qe = (l4 ^ ((l15 >> 1) & 3)) * 8;
    const int lrow = lane >> 2;
    const int csrc = (lane & 3) ^ ((lane >> 3) & 3);
    const int nch = qt + 1;
    // P conversion constants
    const int pr = tid >> 2, pc = (tid & 3) * 16;
    const int psub = (tid >> 1) & 1, pc0 = (tid & 1) * 2;
    const int pswz = (pr >> 1) & 3;

    floatx4 acc[2][2];
#pragma unroll
    for (int i = 0; i < 2; i++)
#pragma unroll
        for (int j = 0; j < 2; j++) acc[i][j] = (floatx4){0.f, 0.f, 0.f, 0.f};

    for (int kc = 0; kc < nch; kc++) {
        __syncthreads();
        // VT via global_load_lds: per wave 16 d-rows, 2 k-subs. VT is indexed by KV head (h>>2)!
#pragma unroll
        for (int sb = 0; sb < 2; sb++) {
            const size_t off = ((size_t)((h >> 2) * 64 + wave * 16 + lrow) * 1024 + kc * 64 + sb * 32) * 2
                               + (size_t)csrc * 16;
            gload_lds16((const char*)VTH + off, &v_h[sb * 2048 + wave * 16 * 32]);
            gload_lds16((const char*)VTL + off, &v_l[sb * 2048 + wave * 16 * 32]);
        }
        // P fp32 -> bf16 hi/lo into LDS
        const float* Prow = probs + ((size_t)(h * 1024) + qt * 64 + pr) * 1024 + kc * 64 + pc;
        const float4 f0 = *(const float4*)(Prow + 0);
        const float4 f1 = *(const float4*)(Prow + 4);
        const float4 f2 = *(const float4*)(Prow + 8);
        const float4 f3 = *(const float4*)(Prow + 12);
        shortx8 h0, l0, h1, l1;
        cvt8(f0, f1, h0, l0);
        cvt8(f2, f3, h1, l1);
        const int st0 = pc0 ^ pswz, st1 = (pc0 + 1) ^ pswz;
        *(shortx8*)&p_h[psub * 2048 + pr * 32 + st0 * 8] = h0;
        *(shortx8*)&p_h[psub * 2048 + pr * 32 + st1 * 8] = h1;
        *(shortx8*)&p_l[psub * 2048 + pr * 32 + st0 * 8] = l0;
        *(shortx8*)&p_l[psub * 2048 + pr * 32 + st1 * 8] = l1;
        __syncthreads();
#pragma unroll
        for (int s = 0; s < 2; s++) {
            shortx8 ah[2], al[2], bh[2], bl[2];
#pragma unroll
            for (int i = 0; i < 2; i++) {
                ah[i] = *(const shortx8*)&p_h[s * 2048 + (wm + i * 16 + l15) * 32 + qe];
                al[i] = *(const shortx8*)&p_l[s * 2048 + (wm + i * 16 + l15) * 32 + qe];
                bh[i] = *(const shortx8*)&v_h[s * 2048 + (wn + i * 16 + l15) * 32 + qe];
                bl[i] = *(const shortx8*)&v_l[s * 2048 + (wn + i * 16 + l15) * 32 + qe];
            }
#pragma unroll
            for (int i = 0; i < 2; i++)
#pragma unroll
                for (int j = 0; j < 2; j++) {
                    acc[i][j] = __builtin_amdgcn_mfma_f32_16x16x32_bf16(ah[i], bh[j], acc[i][j], 0, 0, 0);
                    acc[i][j] = __builtin_amdgcn_mfma_f32_16x16x32_bf16(al[i], bh[j], acc[i][j], 0, 0, 0);
                    acc[i][j] = __builtin_amdgcn_mfma_f32_16x16x32_bf16(ah[i], bl[j], acc[i][j], 0, 0, 0);
                }
        }
    }
#pragma unroll
    for (int j = 0; j < 2; j++) {
        const int col = h * 64 + wn + j * 16 + l15;
#pragma unroll
        for (int i = 0; i < 2; i++) {
#pragma unroll
            for (int r = 0; r < 4; r++) {
                const int row = qt * 64 + wm + i * 16 + l4 * 4 + r;
                obuf[(size_t)row * 2048 + col] = acc[i][j][r];
            }
        }
    }
}

// ---------------- exact quantile: radix select + candidate compaction ----------------
__global__ void sel_init_kernel(unsigned* __restrict__ sel, unsigned* __restrict__ hist,
                                unsigned kA, unsigned kB) {
    const int i = blockIdx.x * 256 + threadIdx.x;
    if (i < 4096) hist[i] = 0u;
    if (i == 0) { sel[0] = 0u; sel[1] = kA; sel[2] = 0u; sel[3] = kB; sel[4] = 0u; }
}

__global__ __launch_bounds__(256) void hist_pass_kernel(const float* __restrict__ vals, long n,
                                                        const unsigned* __restrict__ nptr, unsigned cap,
                                                        const unsigned* __restrict__ sel,
                                                        unsigned* __restrict__ hist,
                                                        int shift, unsigned prefmask) {
    __shared__ unsigned hloc[4096];
    for (int i = threadIdx.x; i < 4096; i += 256) hloc[i] = 0u;
    __syncthreads();
    if (nptr) { unsigned c = *nptr; n = (long)(c < cap ? c : cap); }
    const unsigned prefix = sel[0];
    const long stride = (long)gridDim.x * 256;
    unsigned zcnt = 0;
    for (long i = (long)blockIdx.x * 256 + threadIdx.x; i < n; i += stride) {
        const unsigned b = __float_as_uint(vals[i]);
        if ((b & prefmask) == prefix) {
            if (b == 0u) zcnt++;
            else atomicAdd(&hloc[(b >> shift) & 4095], 1u);
        }
    }
    if (zcnt) atomicAdd(&hloc[0], zcnt);
    __syncthreads();
    for (int i = threadIdx.x; i < 4096; i += 256) if (hloc[i]) atomicAdd(&hist[i], hloc[i]);
}

__global__ __launch_bounds__(256) void compact_kernel(const float* __restrict__ vals, long n,
                                                      const unsigned* __restrict__ selA,
                                                      const unsigned* __restrict__ selB,
                                                      float* __restrict__ cand,
                                                      unsigned* __restrict__ cnt, unsigned cap) {
    const unsigned pa = selA[0], pb = selB[0];
    const long stride = (long)gridDim.x * 256;
    for (long i = (long)blockIdx.x * 256 + threadIdx.x; i < n; i += stride) {
        const float v = vals[i];
        const unsigned b = __float_as_uint(v);
        const unsigned hb = b & 0xFFF00000u;
        if (b != 0u && (hb == pa || hb == pb)) {
            const unsigned idx = atomicAdd(cnt, 1u);
            if (idx < cap) cand[idx] = v;
        }
    }
}

__global__ __launch_bounds__(256) void resolve_pass_kernel(unsigned* __restrict__ sel,
                                                           unsigned* __restrict__ hist,
                                                           int shift, int last,
                                                           float* __restrict__ res, int slot,
                                                           int clear) {
    __shared__ unsigned part[256];
    __shared__ unsigned bpos, boff;
    const int tid = threadIdx.x;
    if (tid == 0) { bpos = 4095u; boff = 0u; }
    unsigned vals[16]; unsigned s = 0;
#pragma unroll
    for (int i = 0; i < 16; i++) { vals[i] = hist[tid * 16 + i]; s += vals[i]; }
    part[tid] = s; __syncthreads();
    for (int off = 1; off < 256; off <<= 1) {
        unsigned v = (tid >= off) ? part[tid - off] : 0u;
        __syncthreads();
        part[tid] += v;
        __syncthreads();
    }
    const unsigned krem = sel[1];
    unsigned c = part[tid] - s;
#pragma unroll
    for (int i = 0; i < 16; i++) {
        if (krem >= c && krem < c + vals[i]) { bpos = tid * 16 + i; boff = krem - c; }
        c += vals[i];
    }
    __syncthreads();
    if (tid == 0) {
        const unsigned p = sel[0] | (bpos << shift);
        sel[0] = p; sel[1] = boff;
        if (last) res[slot] = __uint_as_float(p);
    }
    if (clear) for (int i = 0; i < 16; i++) hist[tid * 16 + i] = 0u;
}

__global__ void finalize_thr_kernel(const float* __restrict__ res, float* __restrict__ out) {
    if (threadIdx.x == 0) out[0] = res[0] + (res[1] - res[0]) * 0.45f;
}

// ---------------- host side ----------------
extern "C" void kernel_launch(void* const* d_in, const int* in_sizes, int n_in,
                              void* d_out, int out_size, void* d_ws, size_t ws_size,
                              hipStream_t stream) {
    (void)in_sizes; (void)n_in; (void)out_size; (void)ws_size;
    const float* x    = (const float*)d_in[0];
    const float* w1   = (const float*)d_in[1];
    const float* w2   = (const float*)d_in[2];
    const float* cosp = (const float*)d_in[3];
    const float* sinp = (const float*)d_in[4];
    const int*   wi_q = (const int*)d_in[6];
    const float* sc_q = (const float*)d_in[7];
    const float* b_q  = (const float*)d_in[8];
    const float* la_q = (const float*)d_in[9];
    const float* lb_q = (const float*)d_in[10];
    const int*   wi_k = (const int*)d_in[11];
    const float* sc_k = (const float*)d_in[12];
    const float* b_k  = (const float*)d_in[13];
    const float* la_k = (const float*)d_in[14];
    const float* lb_k = (const float*)d_in[15];
    const int*   wi_v = (const int*)d_in[16];
    const float* sc_v = (const float*)d_in[17];
    const float* b_v  = (const float*)d_in[18];
    const float* la_v = (const float*)d_in[19];
    const float* lb_v = (const float*)d_in[20];
    const int*   wi_o = (const int*)d_in[21];
    const float* sc_o = (const float*)d_in[22];
    const float* b_o  = (const float*)d_in[23];
    const float* la_o = (const float*)d_in[24];
    const float* lb_o = (const float*)d_in[25];
    const int*   wi_g = (const int*)d_in[26];
    const float* sc_g = (const float*)d_in[27];
    const float* b_g  = (const float*)d_in[28];
    const float* la_g = (const float*)d_in[29];
    const float* lb_g = (const float*)d_in[30];
    const int*   wi_u = (const int*)d_in[31];
    const float* sc_u = (const float*)d_in[32];
    const float* b_u  = (const float*)d_in[33];
    const float* la_u = (const float*)d_in[34];
    const float* lb_u = (const float*)d_in[35];
    const int*   wi_d = (const int*)d_in[36];
    const float* sc_d = (const float*)d_in[37];
    const float* b_d  = (const float*)d_in[38];
    const float* la_d = (const float*)d_in[39];
    const float* lb_d = (const float*)d_in[40];

    float* F    = (float*)d_ws;
    float* XN1  = F + WS_XN1;
    float* Q    = F + WS_Q;
    float* K    = F + WS_KB;
    float* V    = F + WS_VB;
    float* O    = F + WS_OB;
    float* XMED = F + WS_XMED;
    float* XN2  = F + WS_XN2;
    float* PROBS= F + WS_PROBS;
    float* GATE = F + B_GATE;
    float* UP   = F + B_UP;
    float* HAD  = F + B_HAD;
    float* CAND = F + CAND_OFF;
    unsigned* CMX   = (unsigned*)(F + CM_X);
    unsigned* CMXN1 = (unsigned*)(F + CM_XN1);
    unsigned* CMQ   = (unsigned*)(F + CM_Qb);
    unsigned* CMK   = (unsigned*)(F + CM_Kb);
    unsigned* CMV   = (unsigned*)(F + CM_Vb);
    unsigned* CMO   = (unsigned*)(F + CM_Ob);
    unsigned* CMXM  = (unsigned*)(F + CM_XM);
    unsigned* CMXN2 = (unsigned*)(F + CM_XN2b);
    unsigned* CMG   = (unsigned*)(F + CM_GATE);
    unsigned* CMF   = (unsigned*)(F + CM_FN);
    unsigned* CMU   = (unsigned*)(F + CM_UPb);
    unsigned* CMH   = (unsigned*)(F + CM_HAD);
    int*      IDX0  = (int*)(F + WS_IDX);
    int*      IDX1  = IDX0 + 20;
    unsigned* HIST  = (unsigned*)(F + WS_HIST);
    unsigned* SEL   = (unsigned*)(F + WS_SEL);
    float*    RES   = F + WS_RES;
    float*    OUT   = (float*)d_out;
    #define US(off) ((unsigned short*)(F + (off)))

    // 0. zero column-max accumulators
    zero_kernel<<<(CM_TOTAL + 255) / 256, 256, 0, stream>>>(CMX, CM_TOTAL);

    // 1. rmsnorm1 + x channel pack; weights q/k/v -> bf16 (phase A)
    rmsnorm_kernel<<<1024, 256, 0, stream>>>(x, w1, XN1);
    colabsmax_kernel<<<dim3(8, 64), 256, 0, stream>>>(x, 1024, 2048, CMX);
    topk20_kernel<<<1, 256, 0, stream>>>(CMX, OUT + O_XIDX, IDX0);
    packscale_kernel<<<8, 256, 0, stream>>>(CMX, IDX0, OUT + O_XSC, 2048);
    colabsmax_kernel<<<dim3(8, 64), 256, 0, stream>>>(XN1, 1024, 2048, CMXN1);
    w2bf_kernel<<<4096, 256, 0, stream>>>(wi_q, US(A_WQ), 1048576);
    w2bf_kernel<<<1024, 256, 0, stream>>>(wi_k, US(A_WK), 262144);
    w2bf_kernel<<<1024, 256, 0, stream>>>(wi_v, US(A_WV), 262144);

    // 2. q/k/v fused split-K MFMA GEMM
    hilo_kernel<<<2048, 256, 0, stream>>>(XN1, US(A_XN1H), US(A_XN1L), 524288);
    lora_xa_multi_kernel<<<1024, 256, 0, stream>>>(XN1, 2048, 3,
        la_q, US(A_XAQH), US(A_XAQL), la_k, US(A_XAKH), US(A_XAKL), la_v, US(A_XAVH), US(A_XAVL));
    lbt_kernel<<<8, 256, 0, stream>>>(lb_q, sc_q, US(A_LBTQ), 2048);
    lbt_kernel<<<2, 256, 0, stream>>>(lb_k, sc_k, US(A_LBTK), 512);
    lbt_kernel<<<2, 256, 0, stream>>>(lb_v, sc_v, US(A_LBTV), 512);
    zero_kernel<<<12288, 256, 0, stream>>>((unsigned*)Q, 3145728);   // Q,K,V contiguous
    {
        Seg sq{US(A_WQ), US(A_XAQH), US(A_XAQL), US(A_LBTQ), sc_q, b_q, nullptr, Q, 2048, 0};
        Seg sk{US(A_WK), US(A_XAKH), US(A_XAKL), US(A_LBTK), sc_k, b_k, nullptr, K, 512, 16};
        Seg sv{US(A_WV), US(A_XAVH), US(A_XAVL), US(A_LBTV), sc_v, b_v, nullptr, V, 512, 20};
        gemm_mfma3_kernel<<<dim3(24, 8, 2), 256, 0, stream>>>(US(A_XN1H), US(A_XN1L), 2048, 1024, 2, 16, 20, sq, sk, sv);
    }

    // 3. rope (emits bf16 hi/lo) + scales + V transpose
    rope_kernel<<<4096, 256, 0, stream>>>(Q, US(AT_QHG), US(AT_QLG), cosp, sinp, 32);
    rope_kernel<<<1024, 256, 0, stream>>>(K, US(AT_KHG), US(AT_KLG), cosp, sinp, 8);
    colabsmax_kernel<<<dim3(1, 256), 256, 0, stream>>>(Q, 32768, 64, CMQ);
    colabsmax_kernel<<<dim3(1, 128), 256, 0, stream>>>(K, 8192, 64, CMK);
    vtrans_kernel<<<dim3(16, 8), 256, 0, stream>>>(V, US(AT_VTH), US(AT_VTL), CMV);

    // 4. attention (MFMA)
    score_mfma_kernel<<<dim3(36, 32), 256, 0, stream>>>(US(AT_QHG), US(AT_QLG), US(AT_KHG), US(AT_KLG), PROBS);
    softmax_kernel<<<32768, 256, 0, stream>>>(PROBS);
    av_mfma_kernel<<<dim3(16, 32), 256, 0, stream>>>(PROBS, US(AT_VTH), US(AT_VTL), O);
    colabsmax_kernel<<<dim3(8, 64), 256, 0, stream>>>(O, 1024, 2048, CMO);

    // 5. a_thr: ranks 31876709/31876710 of 33554432, frac 0.45
    const long NP = 33554432L;
    sel_init_kernel<<<16, 256, 0, stream>>>(SEL, HIST, 31876709u, 31876710u);
    hist_pass_kernel<<<4096, 256, 0, stream>>>(PROBS, NP, nullptr, 0, SEL + 0, HIST, 20, 0x00000000u);
    resolve_pass_kernel<<<1, 256, 0, stream>>>(SEL + 0, HIST, 20, 0, RES, 0, 0);
    resolve_pass_kernel<<<1, 256, 0, stream>>>(SEL + 2, HIST, 20, 0, RES, 1, 1);
    compact_kernel<<<4096, 256, 0, stream>>>(PROBS, NP, SEL + 0, SEL + 2, CAND, SEL + 4, CAP_CAND);
    hist_pass_kernel<<<256, 256, 0, stream>>>(CAND, 0, SEL + 4, CAP_CAND, SEL + 0, HIST, 8, 0xFFF00000u);
    resolve_pass_kernel<<<1, 256, 0, stream>>>(SEL + 0, HIST, 8, 0, RES, 0, 1);
    hist_pass_kernel<<<256, 256, 0, stream>>>(CAND, 0, SEL + 4, CAP_CAND, SEL + 2, HIST, 8, 0xFFF00000u);
    resolve_pass_kernel<<<1, 256, 0, stream>>>(SEL + 2, HIST, 8, 0, RES, 1, 1);
    hist_pass_kernel<<<256, 256, 0, stream>>>(CAND, 0, SEL + 4, CAP_CAND, SEL + 0, HIST, 0, 0xFFFFFF00u);
    resolve_pass_kernel<<<1, 256, 0, stream>>>(SEL + 0, HIST, 0, 1, RES, 0, 1);
    hist_pass_kernel<<<256, 256, 0, stream>>>(CAND, 0, SEL + 4, CAP_CAND, SEL + 2, HIST, 0, 0xFFFFFF00u);
    resolve_pass_kernel<<<1, 256, 0, stream>>>(SEL + 2, HIST, 0, 1, RES, 1, 1);
    finalize_thr_kernel<<<1, 64, 0, stream>>>(RES, OUT + O_ATHR);

    // 6. o projection (split-K x4, +residual x) -> x_med; pack; rmsnorm2
    w2bf_kernel<<<4096, 256, 0, stream>>>(wi_o, US(B_WO), 1048576);
    hilo_kernel<<<2048, 256, 0, stream>>>(O, US(B_OH), US(B_OL), 524288);
    lora_xa_multi_kernel<<<1024, 256, 0, stream>>>(O, 2048, 1,
        la_o, US(B_XAOH), US(B_XAOL), nullptr, nullptr, nullptr, nullptr, nullptr, nullptr);
    lbt_kernel<<<8, 256, 0, stream>>>(lb_o, sc_o, US(B_LBTO), 2048);
    zero_kernel<<<8192, 256, 0, stream>>>((unsigned*)XMED, 2097152);
    {
        Seg so{US(B_WO), US(B_XAOH), US(B_XAOL), US(B_LBTO), sc_o, b_o, x, XMED, 2048, 0};
        gemm_mfma3_kernel<<<dim3(16, 8, 4), 256, 0, stream>>>(US(B_OH), US(B_OL), 2048, 512, 4, 999, 999, so, so, so);
    }
    colabsmax_kernel<<<dim3(8, 64), 256, 0, stream>>>(XMED, 1024, 2048, CMXM);
    topk20_kernel<<<1, 256, 0, stream>>>(CMXM, OUT + O_XMIDX, IDX1);
    packscale_kernel<<<8, 256, 0, stream>>>(CMXM, IDX1, OUT + O_XMS, 2048);
    rmsnorm_kernel<<<1024, 256, 0, stream>>>(XMED, w2, XN2);
    colabsmax_kernel<<<dim3(8, 64), 256, 0, stream>>>(XN2, 1024, 2048, CMXN2);

    // 7. MLP: gate+up fused GEMM, fused silu/hadamard + 4 col-maxes
    w2bf_kernel<<<11264, 256, 0, stream>>>(wi_g, US(B_WG), 2883584);
    w2bf_kernel<<<11264, 256, 0, stream>>>(wi_u, US(B_WU), 2883584);
    hilo_kernel<<<2048, 256, 0, stream>>>(XN2, US(B_XN2H), US(B_XN2L), 524288);
    lora_xa_multi_kernel<<<1024, 256, 0, stream>>>(XN2, 2048, 2,
        la_g, US(B_XAGH), US(B_XAGL), la_u, US(B_XAUH), US(B_XAUL), nullptr, nullptr, nullptr);
    lbt_kernel<<<22, 256, 0, stream>>>(lb_g, sc_g, US(B_LBTG), 5632);
    lbt_kernel<<<22, 256, 0, stream>>>(lb_u, sc_u, US(B_LBTU), 5632);
    {
        Seg sg{US(B_WG), US(B_XAGH), US(B_XAGL), US(B_LBTG), sc_g, b_g, nullptr, GATE, 5632, 0};
        Seg su{US(B_WU), US(B_XAUH), US(B_XAUL), US(B_LBTU), sc_u, b_u, nullptr, UP, 5632, 44};
        gemm_mfma3_kernel<<<dim3(88, 8, 1), 256, 0, stream>>>(US(B_XN2H), US(B_XN2L), 2048, 2048, 1, 44, 88, sg, su, su);
    }
    w2bf_kernel<<<11264, 256, 0, stream>>>(wi_d, US(B_WD), 2883584);
    hadfuse_kernel<<<dim3(22, 32), 256, 0, stream>>>(GATE, UP, HAD, CMG, CMF, CMU, CMH);

    // 8. down projection (split-K x4, +residual x_med) -> x_out
    hilo_kernel<<<5632, 256, 0, stream>>>(HAD, US(B_HADH), US(B_HADL), 1441792);
    lora_xa_multi_kernel<<<1024, 256, 0, stream>>>(HAD, 5632, 1,
        la_d, US(B_XADH), US(B_XADL), nullptr, nullptr, nullptr, nullptr, nullptr, nullptr);
    lbt_kernel<<<8, 256, 0, stream>>>(lb_d, sc_d, US(B_LBTD), 2048);
    zero_kernel<<<8192, 256, 0, stream>>>((unsigned*)(OUT + O_XOUT), 2097152);
    {
        Seg sd{US(B_WD), US(B_XADH), US(B_XADL), US(B_LBTD), sc_d, b_d, XMED, OUT + O_XOUT, 2048, 0};
        gemm_mfma3_kernel<<<dim3(16, 8, 4), 256, 0, stream>>>(US(B_HADH), US(B_HADL), 5632, 1408, 4, 999, 999, sd, sd, sd);
    }

    // 9. all act_quant scales in one pass
    scale_fin_all_kernel<<<113, 256, 0, stream>>>((const unsigned*)(F + WS_SMALL), OUT);
    #undef US
}

// Round 6
// 1460.591 us; speedup vs baseline: 2.1998x; 2.1998x over previous
//
#include <hip/hip_runtime.h>

// ---------------- problem dims ----------------
// B=1, S=1024, C=2048, H=32, D=64, HKV=8, R=16, FF=5632, Q_BIT=4 (qmax=7)

// ---------------- ws layout (float offsets) ----------------
#define WS_XN1   0L            // also QHG/QLG (bf16) after qkv
#define WS_Q     2097152L      // Q/K/V fp32; dead after step 3 -> CAND region in step 5
#define WS_KB    4194304L
#define WS_VB    4718592L
#define WS_OB    5242880L
#define WS_XMED  7340032L      // also KHG/KLG/VTH/VTL (bf16) during attention
#define WS_XN2   9437184L
#define WS_PROBS 11534336L     // 33554432 floats
// ---- phase A aliases (inside probs; dead before score writes probs) ----
#define PA        WS_PROBS
#define A_WQ      (PA + 0L)
#define A_WK      (PA + 2097152L)
#define A_WV      (PA + 2621440L)
#define A_XN1H    (PA + 3145728L)
#define A_XN1L    (PA + 4194304L)
#define A_XAQH    (PA + 5242880L)
#define A_XAQL    (PA + 5259264L)
#define A_XAKH    (PA + 5275648L)
#define A_XAKL    (PA + 5292032L)
#define A_XAVH    (PA + 5308416L)
#define A_XAVL    (PA + 5324800L)
#define A_LBTQ    (PA + 5341184L)
#define A_LBTK    (PA + 5373952L)
#define A_LBTV    (PA + 5382144L)
// ---- attention bf16 aliases (outside probs) ----
#define AT_QHG    (WS_XN1 + 0L)        // 1024x2048 bf16
#define AT_QLG    (WS_XN1 + 1048576L)
#define AT_KHG    (WS_XMED + 0L)       // 1024x512 bf16
#define AT_KLG    (WS_XMED + 262144L)
#define AT_VTH    (WS_XMED + 524288L)  // 8x64x1024 bf16
#define AT_VTL    (WS_XMED + 786432L)
#define CAND_OFF  WS_Q                 // quantile candidates (Q/K/V fp32 region, dead)
#define CAP_CAND  3145728u
// ---- phase B aliases (inside probs; written only after quantile) ----
#define B_WO      (PA + 0L)
#define B_OH      (PA + 2097152L)
#define B_OL      (PA + 3145728L)
#define B_XAOH    (PA + 4194304L)
#define B_XAOL    (PA + 4210688L)
#define B_LBTO    (PA + 4227072L)
#define B_WG      (PA + 4300800L)
#define B_WU      (PA + 10067968L)
#define B_XN2H    (PA + 15835136L)
#define B_XN2L    (PA + 16883712L)
#define B_XAGH    (PA + 17932288L)
#define B_XAGL    (PA + 17948672L)
#define B_XAUH    (PA + 17965056L)
#define B_XAUL    (PA + 17981440L)
#define B_LBTG    (PA + 17997824L)
#define B_LBTU    (PA + 18087936L)
#define B_GATE    (PA + 18178048L)
#define B_UP      (PA + 23945216L)
#define B_HAD     (PA + 4300800L)      // WG slot
#define B_WD      (PA + 10067968L)     // WU slot
#define B_HADH    (PA + 0L)            // WO+OH slots
#define B_HADL    (PA + 18178048L)     // GATE slot
#define B_XADH    (PA + 15835136L)
#define B_XADL    (PA + 15851520L)
#define B_LBTD    (PA + 15867904L)
// ---- small stuff ----
#define WS_SMALL 45088768L
#define CM_X     (WS_SMALL + 0L)
#define CM_XN1   (WS_SMALL + 2048L)
#define CM_Qb    (WS_SMALL + 4096L)
#define CM_Kb    (WS_SMALL + 4160L)
#define CM_Vb    (WS_SMALL + 4224L)
#define CM_Ob    (WS_SMALL + 4288L)
#define CM_XM    (WS_SMALL + 6336L)
#define CM_XN2b  (WS_SMALL + 8384L)
#define CM_GATE  (WS_SMALL + 10432L)
#define CM_FN    (WS_SMALL + 16064L)
#define CM_UPb   (WS_SMALL + 21696L)
#define CM_HAD   (WS_SMALL + 27328L)
#define CM_TOTAL 32960
#define WS_IDX   (WS_SMALL + 32960L)
#define WS_HIST  (WS_IDX + 64L)
#define WS_SEL   (WS_HIST + 4096L)
#define WS_RES   (WS_SEL + 8L)

// ---------------- out layout (float offsets) ----------------
#define O_XOUT  0L
#define O_XIDX  2097152L
#define O_XSC   2097172L
#define O_XN1S  2099220L
#define O_QS    2101268L
#define O_KS    2101332L
#define O_VS    2101396L
#define O_ATHR  2101460L
#define O_OS    2101461L
#define O_XMIDX 2103509L
#define O_XMS   2103529L
#define O_XN2S  2105577L
#define O_GATES 2107625L
#define O_UPS   2113257L
#define O_FNS   2118889L
#define O_HADS  2124521L

typedef float  floatx4 __attribute__((ext_vector_type(4)));
typedef short  shortx8 __attribute__((ext_vector_type(8)));

static __device__ __forceinline__ unsigned short f2bf(float f) {
    unsigned u = __float_as_uint(f);
    return (unsigned short)((u + 0x7FFFu + ((u >> 16) & 1u)) >> 16);
}
static __device__ __forceinline__ float bf2f(unsigned short b) {
    return __uint_as_float(((unsigned)b) << 16);
}
static __device__ __forceinline__ void gload_lds16(const void* g, void* l) {
    __builtin_amdgcn_global_load_lds(
        (const __attribute__((address_space(1))) unsigned int*)g,
        (__attribute__((address_space(3))) unsigned int*)l, 16, 0, 0);
}
static __device__ __forceinline__ void cvt8(const float4 a, const float4 b,
                                            shortx8& h8, shortx8& l8) {
    float v[8] = {a.x, a.y, a.z, a.w, b.x, b.y, b.z, b.w};
#pragma unroll
    for (int i = 0; i < 8; i++) {
        unsigned short h = f2bf(v[i]);
        h8[i] = (short)h;
        l8[i] = (short)f2bf(v[i] - bf2f(h));
    }
}

// ---------------- small utility kernels ----------------
__global__ void zero_kernel(unsigned* __restrict__ p, int n) {
    int i = blockIdx.x * 256 + threadIdx.x;
    if (i < n) p[i] = 0u;
}

__global__ __launch_bounds__(256) void rmsnorm_kernel(const float* __restrict__ x,
                                                      const float* __restrict__ w,
                                                      float* __restrict__ out) {
    const int row = blockIdx.x;
    const int tid = threadIdx.x;
    const float* xr = x + row * 2048;
    float s = 0.f;
    for (int i = tid; i < 2048; i += 256) { float v = xr[i]; s += v * v; }
    __shared__ float red[256];
    red[tid] = s; __syncthreads();
    for (int off = 128; off; off >>= 1) { if (tid < off) red[tid] += red[tid + off]; __syncthreads(); }
    const float rstd = 1.0f / sqrtf(red[0] / 2048.0f + 1e-5f);
    float* orow = out + row * 2048;
    for (int i = tid; i < 2048; i += 256) orow[i] = xr[i] * rstd * w[i];
}

__global__ void colabsmax_kernel(const float* __restrict__ in, int M, int N,
                                 unsigned* __restrict__ outb) {
    const int c = blockIdx.x * 256 + threadIdx.x;
    if (c >= N) return;
    float loc = 0.f;
    for (int r = blockIdx.y; r < M; r += gridDim.y)
        loc = fmaxf(loc, fabsf(in[(long)r * N + c]));
    atomicMax(outb + c, __float_as_uint(loc));
}

__global__ __launch_bounds__(256) void scale_fin_all_kernel(const unsigned* __restrict__ cm,
                                                            float* __restrict__ OUT) {
    int i = blockIdx.x * 256 + threadIdx.x;
    const int  n[10]  = {2048, 64, 64, 64, 2048, 2048, 5632, 5632, 5632, 5632};
    const int  co[10] = {2048, 4096, 4160, 4224, 4288, 8384, 10432, 16064, 21696, 27328};
    const long oo[10] = {O_XN1S, O_QS, O_KS, O_VS, O_OS, O_XN2S, O_GATES, O_FNS, O_UPS, O_HADS};
#pragma unroll
    for (int s = 0; s < 10; s++) {
        if (i < n[s]) { OUT[oo[s] + i] = __uint_as_float(cm[co[s] + i]) / 7.0f + 1e-8f; return; }
        i -= n[s];
    }
}

__global__ __launch_bounds__(256) void topk20_kernel(const unsigned* __restrict__ cmaxbits,
                                                     float* __restrict__ out_idx_f,
                                                     int* __restrict__ out_idx_i) {
    __shared__ float vals[2048];
    __shared__ float rv[256];
    __shared__ int   ri[256];
    const int tid = threadIdx.x;
    for (int i = tid; i < 2048; i += 256) vals[i] = __uint_as_float(cmaxbits[i]);
    __syncthreads();
    for (int t = 0; t < 20; t++) {
        float bv = -1.f; int bi = 1 << 30;
        for (int i = tid; i < 2048; i += 256) {
            float v = vals[i];
            if (v > bv) { bv = v; bi = i; }
        }
        rv[tid] = bv; ri[tid] = bi; __syncthreads();
        for (int off = 128; off; off >>= 1) {
            if (tid < off) {
                float v2 = rv[tid + off]; int i2 = ri[tid + off];
                if (v2 > rv[tid] || (v2 == rv[tid] && i2 < ri[tid])) { rv[tid] = v2; ri[tid] = i2; }
            }
            __syncthreads();
        }
        if (tid == 0) { out_idx_f[t] = (float)ri[0]; out_idx_i[t] = ri[0]; vals[ri[0]] = -1.f; }
        __syncthreads();
    }
}

__global__ void packscale_kernel(const unsigned* __restrict__ cmaxbits,
                                 const int* __restrict__ idx, float* __restrict__ out, int n) {
    const int c = blockIdx.x * 256 + threadIdx.x;
    if (c >= n) return;
    bool outl = false;
    for (int t = 0; t < 20; t++) outl |= (idx[t] == c);
    const float m = __uint_as_float(cmaxbits[c]);
    out[c] = outl ? 1e-8f : (m / 7.0f + 1e-8f);
}

// up to 3 LoRA xa projections in one pass over A
__global__ __launch_bounds__(256) void lora_xa_multi_kernel(
    const float* __restrict__ A, int K, int nset,
    const float* __restrict__ la0, unsigned short* __restrict__ xh0, unsigned short* __restrict__ xl0,
    const float* __restrict__ la1, unsigned short* __restrict__ xh1, unsigned short* __restrict__ xl1,
    const float* __restrict__ la2, unsigned short* __restrict__ xh2, unsigned short* __restrict__ xl2) {
    const int m = blockIdx.x;
    const int tid = threadIdx.x;
    const int r = tid & 15, g = tid >> 4;
    float s0 = 0.f, s1 = 0.f, s2 = 0.f;
    const float* Am = A + (long)m * K;
    for (int k = g; k < K; k += 16) {
        const float a = Am[k];
        s0 += a * la0[k * 16 + r];
        if (nset > 1) s1 += a * la1[k * 16 + r];
        if (nset > 2) s2 += a * la2[k * 16 + r];
    }
    __shared__ float red[768];
    red[tid] = s0; red[256 + tid] = s1; red[512 + tid] = s2; __syncthreads();
    for (int off = 128; off >= 16; off >>= 1) {
        if (tid < off) {
            red[tid] += red[tid + off];
            red[256 + tid] += red[256 + tid + off];
            red[512 + tid] += red[512 + tid + off];
        }
        __syncthreads();
    }
    if (tid < 16) {
        float v = red[tid]; unsigned short h = f2bf(v);
        xh0[m * 32 + tid] = h; xl0[m * 32 + tid] = f2bf(v - bf2f(h));
        if (nset > 1) { v = red[256 + tid]; h = f2bf(v); xh1[m * 32 + tid] = h; xl1[m * 32 + tid] = f2bf(v - bf2f(h)); }
        if (nset > 2) { v = red[512 + tid]; h = f2bf(v); xh2[m * 32 + tid] = h; xl2[m * 32 + tid] = f2bf(v - bf2f(h)); }
    } else if (tid < 32) {
        xh0[m * 32 + tid] = 0; xl0[m * 32 + tid] = 0;
        if (nset > 1) { xh1[m * 32 + tid] = 0; xl1[m * 32 + tid] = 0; }
        if (nset > 2) { xh2[m * 32 + tid] = 0; xl2[m * 32 + tid] = 0; }
    }
}

__global__ void hilo_kernel(const float* __restrict__ in, unsigned short* __restrict__ hi,
                            unsigned short* __restrict__ lo, long n4) {
    const long i = (long)blockIdx.x * 256 + threadIdx.x;
    if (i >= n4) return;
    const float4 v = *(const float4*)(in + i * 4);
    ushort4 h, l;
    h.x = f2bf(v.x); l.x = f2bf(v.x - bf2f(h.x));
    h.y = f2bf(v.y); l.y = f2bf(v.y - bf2f(h.y));
    h.z = f2bf(v.z); l.z = f2bf(v.z - bf2f(h.z));
    h.w = f2bf(v.w); l.w = f2bf(v.w - bf2f(h.w));
    *(ushort4*)(hi + i * 4) = h;
    *(ushort4*)(lo + i * 4) = l;
}

__global__ void w2bf_kernel(const int* __restrict__ wi, unsigned short* __restrict__ out, long n4) {
    const long i = (long)blockIdx.x * 256 + threadIdx.x;
    if (i >= n4) return;
    const int4 w = *(const int4*)(wi + i * 4);
    ushort4 o;
    o.x = (unsigned short)(__float_as_uint((float)w.x) >> 16);
    o.y = (unsigned short)(__float_as_uint((float)w.y) >> 16);
    o.z = (unsigned short)(__float_as_uint((float)w.z) >> 16);
    o.w = (unsigned short)(__float_as_uint((float)w.w) >> 16);
    *(ushort4*)(out + i * 4) = o;
}

__global__ void lbt_kernel(const float* __restrict__ lb, const float* __restrict__ sc,
                           unsigned short* __restrict__ out, int N) {
    const int n = blockIdx.x * 256 + threadIdx.x;
    if (n >= N) return;
    const float inv = 1.0f / sc[n];
    for (int r = 0; r < 16; r++) out[n * 32 + r] = f2bf(lb[r * N + n] * inv);
    for (int r = 16; r < 32; r++) out[n * 32 + r] = 0;
}

// rope in-place + emit bf16 hi/lo copies
__global__ void rope_kernel(float* __restrict__ x, unsigned short* __restrict__ xh,
                            unsigned short* __restrict__ xl,
                            const float* __restrict__ cs, const float* __restrict__ sn, int nh) {
    const int idx = blockIdx.x * 256 + threadIdx.x;
    const int tot = 1024 * nh * 32;
    if (idx >= tot) return;
    const int d = idx & 31;
    const int h = (idx >> 5) % nh;
    const int s = (idx >> 5) / nh;
    const long e = (long)s * (nh * 64) + h * 64 + d;
    const float x1 = x[e], x2 = x[e + 32];
    const float c1 = cs[s * 64 + d],      s1 = sn[s * 64 + d];
    const float c2 = cs[s * 64 + d + 32], s2 = sn[s * 64 + d + 32];
    const float v1 = x1 * c1 - x2 * s1;
    const float v2 = x2 * c2 + x1 * s2;
    x[e] = v1; x[e + 32] = v2;
    unsigned short h1 = f2bf(v1), h2 = f2bf(v2);
    xh[e] = h1;      xl[e] = f2bf(v1 - bf2f(h1));
    xh[e + 32] = h2; xl[e + 32] = f2bf(v2 - bf2f(h2));
}

// V -> VT (bf16 hi/lo, [kvh][64 d][1024 s]) + per-d abs-max
__global__ __launch_bounds__(256) void vtrans_kernel(const float* __restrict__ V,
                                                     unsigned short* __restrict__ vth,
                                                     unsigned short* __restrict__ vtl,
                                                     unsigned* __restrict__ cmv) {
    __shared__ float T[64][65];
    __shared__ unsigned vmax[64];
    const int st = blockIdx.x, h = blockIdx.y, t = threadIdx.x;
    if (t < 64) vmax[t] = 0u;
    const int r = t >> 2, cb = (t & 3) * 16;
    const float* src = V + (size_t)(st * 64 + r) * 512 + h * 64 + cb;
#pragma unroll
    for (int i = 0; i < 4; i++) {
        const float4 v = *(const float4*)(src + i * 4);
        T[r][cb + i * 4 + 0] = v.x; T[r][cb + i * 4 + 1] = v.y;
        T[r][cb + i * 4 + 2] = v.z; T[r][cb + i * 4 + 3] = v.w;
    }
    __syncthreads();
    const int dd = t >> 2, sb = (t & 3) * 16;
    shortx8 th0, th1, tl0, tl1;
    float mx = 0.f;
#pragma unroll
    for (int i = 0; i < 16; i++) {
        const float f = T[sb + i][dd];
        mx = fmaxf(mx, fabsf(f));
        const unsigned short hh = f2bf(f);
        const unsigned short ll = f2bf(f - bf2f(hh));
        if (i < 8) { th0[i] = (short)hh; tl0[i] = (short)ll; }
        else       { th1[i - 8] = (short)hh; tl1[i - 8] = (short)ll; }
    }
    atomicMax(&vmax[dd], __float_as_uint(mx));
    const size_t off = (size_t)(h * 64 + dd) * 1024 + st * 64 + sb;
    *(shortx8*)&vth[off] = th0; *(shortx8*)&vth[off + 8] = th1;
    *(shortx8*)&vtl[off] = tl0; *(shortx8*)&vtl[off + 8] = tl1;
    __syncthreads();
    if (t < 64) atomicMax(cmv + t, vmax[t]);
}

// gate/up -> had + 4 column abs-maxes
__global__ __launch_bounds__(256) void hadfuse_kernel(const float* __restrict__ gate,
                                                      const float* __restrict__ up,
                                                      float* __restrict__ had,
                                                      unsigned* __restrict__ cmg, unsigned* __restrict__ cmf,
                                                      unsigned* __restrict__ cmu, unsigned* __restrict__ cmh) {
    const int c = blockIdx.x * 256 + threadIdx.x;
    if (c >= 5632) return;
    float mg = 0.f, mf = 0.f, mu = 0.f, mh = 0.f;
    for (int r = blockIdx.y; r < 1024; r += gridDim.y) {
        const float g = gate[(long)r * 5632 + c];
        const float u = up[(long)r * 5632 + c];
        const float fn = g / (1.f + expf(-g));
        const float hv = u * fn;
        had[(long)r * 5632 + c] = hv;
        mg = fmaxf(mg, fabsf(g)); mf = fmaxf(mf, fabsf(fn));
        mu = fmaxf(mu, fabsf(u)); mh = fmaxf(mh, fabsf(hv));
    }
    atomicMax(cmg + c, __float_as_uint(mg));
    atomicMax(cmf + c, __float_as_uint(mf));
    atomicMax(cmu + c, __float_as_uint(mu));
    atomicMax(cmh + c, __float_as_uint(mh));
}

// ---------------- MFMA GEMM with split-K ----------------
struct Seg {
    const unsigned short *W, *xh, *xl, *lbt;
    const float *sc, *b, *res;
    float *C;
    int N;
    int bx0;
};

__global__ __launch_bounds__(256) void gemm_mfma3_kernel(
    const unsigned short* __restrict__ Ah, const unsigned short* __restrict__ Al,
    int K, int Kc, int KS, int c1, int c2, Seg s0, Seg s1, Seg s2)
{
    __shared__ unsigned short lds[2][3][4096];   // dbuf x {AH, AL, B} x 8KB
    const int tid  = threadIdx.x;
    const int wave = tid >> 6, lane = tid & 63;
    const Seg s = (blockIdx.x < c1) ? s0 : (blockIdx.x < c2) ? s1 : s2;
    const int bn = (blockIdx.x - s.bx0) * 128;
    const int bm = blockIdx.y * 128;
    const int z  = blockIdx.z;
    const int wm = (wave >> 1) * 64, wn = (wave & 1) * 64;
    const int l15 = lane & 15, l4 = lane >> 4;
    const int qe = (l4 ^ ((l15 >> 1) & 3)) * 8;
    const int lrow = lane >> 2;
    const int csrc = (lane & 3) ^ ((lane >> 3) & 3);
    const size_t strideMain = (size_t)K * 2;
    const int iters = Kc >> 5;
    const int nsteps = iters + (z == 0 ? 1 : 0);

    floatx4 acc[4][4];
#pragma unroll
    for (int i = 0; i < 4; i++)
#pragma unroll
        for (int j = 0; j < 4; j++) acc[i][j] = (floatx4){0.f, 0.f, 0.f, 0.f};

    auto load3 = [&](int it, int buf) {
        const char *pAh, *pAl, *pB; size_t stA, stB, kb;
        if (it < iters) {
            pAh = (const char*)Ah; pAl = (const char*)Al; pB = (const char*)s.W;
            stA = strideMain; stB = strideMain; kb = (size_t)(z * Kc + it * 32) * 2;
        } else {
            pAh = (const char*)s.xh; pAl = (const char*)s.xl; pB = (const char*)s.lbt;
            stA = 64; stB = 64; kb = 0;
        }
#pragma unroll
        for (int issue = 0; issue < 2; issue++) {
            const int rt = wave * 32 + issue * 16 + lrow;
            const size_t co = kb + (size_t)csrc * 16;
            unsigned short* d0 = &lds[buf][0][(wave * 32 + issue * 16) * 32];
            unsigned short* d1 = &lds[buf][1][(wave * 32 + issue * 16) * 32];
            unsigned short* d2 = &lds[buf][2][(wave * 32 + issue * 16) * 32];
            gload_lds16(pAh + (size_t)(bm + rt) * stA + co, d0);
            gload_lds16(pAl + (size_t)(bm + rt) * stA + co, d1);
            gload_lds16(pB  + (size_t)(bn + rt) * stB + co, d2);
        }
    };

    load3(0, 0);
    for (int it = 0; it < nsteps; it++) {
        const int cur = it & 1;
        __syncthreads();
        if (it + 1 < nsteps) load3(it + 1, cur ^ 1);
        const unsigned short* tAh = lds[cur][0];
        const unsigned short* tAl = lds[cur][1];
        const unsigned short* tB  = lds[cur][2];
        shortx8 afh[4], afl[4], bfr[4];
#pragma unroll
        for (int i = 0; i < 4; i++) {
            afh[i] = *(const shortx8*)&tAh[(wm + i * 16 + l15) * 32 + qe];
            afl[i] = *(const shortx8*)&tAl[(wm + i * 16 + l15) * 32 + qe];
            bfr[i] = *(const shortx8*)&tB [(wn + i * 16 + l15) * 32 + qe];
        }
#pragma unroll
        for (int i = 0; i < 4; i++)
#pragma unroll
            for (int j = 0; j < 4; j++) {
                acc[i][j] = __builtin_amdgcn_mfma_f32_16x16x32_bf16(afh[i], bfr[j], acc[i][j], 0, 0, 0);
                acc[i][j] = __builtin_amdgcn_mfma_f32_16x16x32_bf16(afl[i], bfr[j], acc[i][j], 0, 0, 0);
            }
    }

#pragma unroll
    for (int j = 0; j < 4; j++) {
        const int n = bn + wn + j * 16 + l15;
        const float scn = s.sc[n];
        const float bsn = (z == 0) ? s.b[n] : 0.f;
#pragma unroll
        for (int i = 0; i < 4; i++) {
            const int m0 = bm + wm + i * 16 + l4 * 4;
#pragma unroll
            for (int r = 0; r < 4; r++) {
                const int m = m0 + r;
                float v = acc[i][j][r] * scn + bsn;
                if (z == 0 && s.res) v += s.res[(size_t)m * s.N + n];
                if (KS == 1) s.C[(size_t)m * s.N + n] = v;
                else atomicAdd(&s.C[(size_t)m * s.N + n], v);
            }
        }
    }
}

// ---------------- attention: MFMA score (lower-triangle 128x128 tiles) ----------------
__global__ __launch_bounds__(256) void score_mfma_kernel(
    const unsigned short* __restrict__ QH, const unsigned short* __restrict__ QL,
    const unsigned short* __restrict__ KH, const unsigned short* __restrict__ KL,
    float* __restrict__ probs)
{
    __shared__ unsigned short q_h[4096], q_l[4096], k_h[4096], k_l[4096];
    const int tid = threadIdx.x, wave = tid >> 6, lane = tid & 63;
    const int t = blockIdx.x, h = blockIdx.y;
    int by = 0;
    while ((by + 1) * (by + 2) / 2 <= t) by++;
    const int bx = t - by * (by + 1) / 2;
    const int wm = (wave >> 1) * 64, wn = (wave & 1) * 64;
    const int l15 = lane & 15, l4 = lane >> 4;
    const int qe = (l4 ^ ((l15 >> 1) & 3)) * 8;
    const int lrow = lane >> 2;
    const int csrc = (lane & 3) ^ ((lane >> 3) & 3);

    floatx4 acc[4][4];
#pragma unroll
    for (int i = 0; i < 4; i++)
#pragma unroll
        for (int j = 0; j < 4; j++) acc[i][j] = (floatx4){0.f, 0.f, 0.f, 0.f};

    for (int s = 0; s < 2; s++) {
        __syncthreads();
#pragma unroll
        for (int issue = 0; issue < 2; issue++) {
            const int rq = by * 128 + wave * 32 + issue * 16 + lrow;
            const int rk = bx * 128 + wave * 32 + issue * 16 + lrow;
            const size_t coq = ((size_t)rq * 2048 + h * 64 + s * 32) * 2 + (size_t)csrc * 16;
            const size_t cok = ((size_t)rk * 512 + (h >> 2) * 64 + s * 32) * 2 + (size_t)csrc * 16;
            const int db = (wave * 32 + issue * 16) * 32;
            gload_lds16((const char*)QH + coq, &q_h[db]);
            gload_lds16((const char*)QL + coq, &q_l[db]);
            gload_lds16((const char*)KH + cok, &k_h[db]);
            gload_lds16((const char*)KL + cok, &k_l[db]);
        }
        __syncthreads();
        shortx8 ah[4], al[4], bh[4], bl[4];
#pragma unroll
        for (int i = 0; i < 4; i++) {
            ah[i] = *(const shortx8*)&q_h[(wm + i * 16 + l15) * 32 + qe];
            al[i] = *(const shortx8*)&q_l[(wm + i * 16 + l15) * 32 + qe];
            bh[i] = *(const shortx8*)&k_h[(wn + i * 16 + l15) * 32 + qe];
            bl[i] = *(const shortx8*)&k_l[(wn + i * 16 + l15) * 32 + qe];
        }
#pragma unroll
        for (int i = 0; i < 4; i++)
#pragma unroll
            for (int j = 0; j < 4; j++) {
                acc[i][j] = __builtin_amdgcn_mfma_f32_16x16x32_bf16(ah[i], bh[j], acc[i][j], 0, 0, 0);
                acc[i][j] = __builtin_amdgcn_mfma_f32_16x16x32_bf16(al[i], bh[j], acc[i][j], 0, 0, 0);
                acc[i][j] = __builtin_amdgcn_mfma_f32_16x16x32_bf16(ah[i], bl[j], acc[i][j], 0, 0, 0);
            }
    }
#pragma unroll
    for (int j = 0; j < 4; j++) {
        const int col = bx * 128 + wn + j * 16 + l15;
#pragma unroll
        for (int i = 0; i < 4; i++) {
#pragma unroll
            for (int r = 0; r < 4; r++) {
                const int row = by * 128 + wm + i * 16 + l4 * 4 + r;
                probs[((size_t)(h * 1024) + row) * 1024 + col] = acc[i][j][r] * 0.125f;
            }
        }
    }
}

__global__ __launch_bounds__(256) void softmax_kernel(float* __restrict__ probs) {
    const int row = blockIdx.x;
    const int qi = row & 1023;
    float* p = probs + (long)row * 1024;
    const int tid = threadIdx.x;
    __shared__ float red[256];
    float m = -3.4e38f;
    for (int i = tid; i <= qi; i += 256) m = fmaxf(m, p[i]);
    red[tid] = m; __syncthreads();
    for (int off = 128; off; off >>= 1) { if (tid < off) red[tid] = fmaxf(red[tid], red[tid + off]); __syncthreads(); }
    m = red[0]; __syncthreads();
    float s = 0.f;
    for (int i = tid; i <= qi; i += 256) { float e = expf(p[i] - m); p[i] = e; s += e; }
    red[tid] = s; __syncthreads();
    for (int off = 128; off; off >>= 1) { if (tid < off) red[tid] += red[tid + off]; __syncthreads(); }
    const float inv = 1.f / red[0];
    for (int i = tid; i < 1024; i += 256) p[i] = (i <= qi) ? p[i] * inv : 0.f;
}

// ---------------- attention: MFMA AV (64-row q tiles) ----------------
__global__ __launch_bounds__(256) void av_mfma_kernel(
    const float* __restrict__ probs,
    const unsigned short* __restrict__ VTH, const unsigned short* __restrict__ VTL,
    float* __restrict__ obuf)
{
    __shared__ unsigned short p_h[4096], p_l[4096];   // [2 sub][64][32]
    __shared__ unsigned short v_h[4096], v_l[4096];
    const int tid = threadIdx.x, wave = tid >> 6, lane = tid & 63;
    const int qt = blockIdx.x, h = blockIdx.y;
    const int wm = (wave >> 1) * 32, wn = (wave & 1) * 32;
    const int l15 = lane & 15, l4 = lane >> 4;
    const int qe = (l4 ^ ((l15 >> 1) & 3)) * 8;
    const int lrow = lane >> 2;
    const int csrc = (lane & 3) ^ ((lane >> 3) & 3);
    const int nch = qt + 1;
    // P conversion constants
    const int pr = tid >> 2, pc = (tid & 3) * 16;
    const int psub = (tid >> 1) & 1, pc0 = (tid & 1) * 2;
    const int pswz = (pr >> 1) & 3;

    floatx4 acc[2][2];
#pragma unroll
    for (int i = 0; i < 2; i++)
#pragma unroll
        for (int j = 0; j < 2; j++) acc[i][j] = (floatx4){0.f, 0.f, 0.f, 0.f};

    for (int kc = 0; kc < nch; kc++) {
        __syncthreads();
        // VT via global_load_lds: per wave 16 d-rows, 2 k-subs. VT is indexed by KV head (h>>2)!
#pragma unroll
        for (int sb = 0; sb < 2; sb++) {
            const size_t off = ((size_t)((h >> 2) * 64 + wave * 16 + lrow) * 1024 + kc * 64 + sb * 32) * 2
                               + (size_t)csrc * 16;
            gload_lds16((const char*)VTH + off, &v_h[sb * 2048 + wave * 16 * 32]);
            gload_lds16((const char*)VTL + off, &v_l[sb * 2048 + wave * 16 * 32]);
        }
        // P fp32 -> bf16 hi/lo into LDS
        const float* Prow = probs + ((size_t)(h * 1024) + qt * 64 + pr) * 1024 + kc * 64 + pc;
        const float4 f0 = *(const float4*)(Prow + 0);
        const float4 f1 = *(const float4*)(Prow + 4);
        const float4 f2 = *(const float4*)(Prow + 8);
        const float4 f3 = *(const float4*)(Prow + 12);
        shortx8 h0, l0, h1, l1;
        cvt8(f0, f1, h0, l0);
        cvt8(f2, f3, h1, l1);
        const int st0 = pc0 ^ pswz, st1 = (pc0 + 1) ^ pswz;
        *(shortx8*)&p_h[psub * 2048 + pr * 32 + st0 * 8] = h0;
        *(shortx8*)&p_h[psub * 2048 + pr * 32 + st1 * 8] = h1;
        *(shortx8*)&p_l[psub * 2048 + pr * 32 + st0 * 8] = l0;
        *(shortx8*)&p_l[psub * 2048 + pr * 32 + st1 * 8] = l1;
        __syncthreads();
#pragma unroll
        for (int s = 0; s < 2; s++) {
            shortx8 ah[2], al[2], bh[2], bl[2];
#pragma unroll
            for (int i = 0; i < 2; i++) {
                ah[i] = *(const shortx8*)&p_h[s * 2048 + (wm + i * 16 + l15) * 32 + qe];
                al[i] = *(const shortx8*)&p_l[s * 2048 + (wm + i * 16 + l15) * 32 + qe];
                bh[i] = *(const shortx8*)&v_h[s * 2048 + (wn + i * 16 + l15) * 32 + qe];
                bl[i] = *(const shortx8*)&v_l[s * 2048 + (wn + i * 16 + l15) * 32 + qe];
            }
#pragma unroll
            for (int i = 0; i < 2; i++)
#pragma unroll
                for (int j = 0; j < 2; j++) {
                    acc[i][j] = __builtin_amdgcn_mfma_f32_16x16x32_bf16(ah[i], bh[j], acc[i][j], 0, 0, 0);
                    acc[i][j] = __builtin_amdgcn_mfma_f32_16x16x32_bf16(al[i], bh[j], acc[i][j], 0, 0, 0);
                    acc[i][j] = __builtin_amdgcn_mfma_f32_16x16x32_bf16(ah[i], bl[j], acc[i][j], 0, 0, 0);
                }
        }
    }
#pragma unroll
    for (int j = 0; j < 2; j++) {
        const int col = h * 64 + wn + j * 16 + l15;
#pragma unroll
        for (int i = 0; i < 2; i++) {
#pragma unroll
            for (int r = 0; r < 4; r++) {
                const int row = qt * 64 + wm + i * 16 + l4 * 4 + r;
                obuf[(size_t)row * 2048 + col] = acc[i][j][r];
            }
        }
    }
}

// ---------------- exact quantile: radix select + candidate compaction ----------------
__global__ void sel_init_kernel(unsigned* __restrict__ sel, unsigned* __restrict__ hist,
                                unsigned kA, unsigned kB) {
    const int i = blockIdx.x * 256 + threadIdx.x;
    if (i < 4096) hist[i] = 0u;
    if (i == 0) { sel[0] = 0u; sel[1] = kA; sel[2] = 0u; sel[3] = kB; sel[4] = 0u; }
}

__global__ __launch_bounds__(256) void hist_pass_kernel(const float* __restrict__ vals, long n,
                                                        const unsigned* __restrict__ nptr, unsigned cap,
                                                        const unsigned* __restrict__ sel,
                                                        unsigned* __restrict__ hist,
                                                        int shift, unsigned prefmask) {
    __shared__ unsigned hloc[4096];
    for (int i = threadIdx.x; i < 4096; i += 256) hloc[i] = 0u;
    __syncthreads();
    if (nptr) { unsigned c = *nptr; n = (long)(c < cap ? c : cap); }
    const unsigned prefix = sel[0];
    const long stride = (long)gridDim.x * 256;
    unsigned zcnt = 0;
    for (long i = (long)blockIdx.x * 256 + threadIdx.x; i < n; i += stride) {
        const unsigned b = __float_as_uint(vals[i]);
        if ((b & prefmask) == prefix) {
            if (b == 0u) zcnt++;
            else atomicAdd(&hloc[(b >> shift) & 4095], 1u);
        }
    }
    if (zcnt) atomicAdd(&hloc[0], zcnt);
    __syncthreads();
    for (int i = threadIdx.x; i < 4096; i += 256) if (hloc[i]) atomicAdd(&hist[i], hloc[i]);
}

// block-aggregated compaction: LDS staging buffer, ONE global atomic per block
// (round-5 version did one global atomic per match on a single address -> 1.8 ms)
__global__ __launch_bounds__(256) void compact_kernel(const float* __restrict__ vals, long n,
                                                      const unsigned* __restrict__ selA,
                                                      const unsigned* __restrict__ selB,
                                                      float* __restrict__ cand,
                                                      unsigned* __restrict__ cnt, unsigned cap) {
    __shared__ float buf[4096];
    __shared__ unsigned lcnt, gbase;
    if (threadIdx.x == 0) lcnt = 0u;
    __syncthreads();
    const unsigned pa = selA[0], pb = selB[0];
    const long stride = (long)gridDim.x * 256;
    for (long i = (long)blockIdx.x * 256 + threadIdx.x; i < n; i += stride) {
        const float v = vals[i];
        const unsigned b = __float_as_uint(v);
        const unsigned hb = b & 0xFFF00000u;
        if (b != 0u && (hb == pa || hb == pb)) {
            const unsigned idx = atomicAdd(&lcnt, 1u);
            if (idx < 4096u) buf[idx] = v;
            else {   // rare overflow: direct append (exact count preserved)
                const unsigned g = atomicAdd(cnt, 1u);
                if (g < cap) cand[g] = v;
            }
        }
    }
    __syncthreads();
    if (threadIdx.x == 0) {
        const unsigned c = lcnt < 4096u ? lcnt : 4096u;
        gbase = atomicAdd(cnt, c);
    }
    __syncthreads();
    const unsigned c = lcnt < 4096u ? lcnt : 4096u;
    for (unsigned j = threadIdx.x; j < c; j += 256) {
        const unsigned idx = gbase + j;
        if (idx < cap) cand[idx] = buf[j];
    }
}

__global__ __launch_bounds__(256) void resolve_pass_kernel(unsigned* __restrict__ sel,
                                                           unsigned* __restrict__ hist,
                                                           int shift, int last,
                                                           float* __restrict__ res, int slot,
                                                           int clear) {
    __shared__ unsigned part[256];
    __shared__ unsigned bpos, boff;
    const int tid = threadIdx.x;
    if (tid == 0) { bpos = 4095u; boff = 0u; }
    unsigned vals[16]; unsigned s = 0;
#pragma unroll
    for (int i = 0; i < 16; i++) { vals[i] = hist[tid * 16 + i]; s += vals[i]; }
    part[tid] = s; __syncthreads();
    for (int off = 1; off < 256; off <<= 1) {
        unsigned v = (tid >= off) ? part[tid - off] : 0u;
        __syncthreads();
        part[tid] += v;
        __syncthreads();
    }
    const unsigned krem = sel[1];
    unsigned c = part[tid] - s;
#pragma unroll
    for (int i = 0; i < 16; i++) {
        if (krem >= c && krem < c + vals[i]) { bpos = tid * 16 + i; boff = krem - c; }
        c += vals[i];
    }
    __syncthreads();
    if (tid == 0) {
        const unsigned p = sel[0] | (bpos << shift);
        sel[0] = p; sel[1] = boff;
        if (last) res[slot] = __uint_as_float(p);
    }
    if (clear) for (int i = 0; i < 16; i++) hist[tid * 16 + i] = 0u;
}

__global__ void finalize_thr_kernel(const float* __restrict__ res, float* __restrict__ out) {
    if (threadIdx.x == 0) out[0] = res[0] + (res[1] - res[0]) * 0.45f;
}

// ---------------- host side ----------------
extern "C" void kernel_launch(void* const* d_in, const int* in_sizes, int n_in,
                              void* d_out, int out_size, void* d_ws, size_t ws_size,
                              hipStream_t stream) {
    (void)in_sizes; (void)n_in; (void)out_size; (void)ws_size;
    const float* x    = (const float*)d_in[0];
    const float* w1   = (const float*)d_in[1];
    const float* w2   = (const float*)d_in[2];
    const float* cosp = (const float*)d_in[3];
    const float* sinp = (const float*)d_in[4];
    const int*   wi_q = (const int*)d_in[6];
    const float* sc_q = (const float*)d_in[7];
    const float* b_q  = (const float*)d_in[8];
    const float* la_q = (const float*)d_in[9];
    const float* lb_q = (const float*)d_in[10];
    const int*   wi_k = (const int*)d_in[11];
    const float* sc_k = (const float*)d_in[12];
    const float* b_k  = (const float*)d_in[13];
    const float* la_k = (const float*)d_in[14];
    const float* lb_k = (const float*)d_in[15];
    const int*   wi_v = (const int*)d_in[16];
    const float* sc_v = (const float*)d_in[17];
    const float* b_v  = (const float*)d_in[18];
    const float* la_v = (const float*)d_in[19];
    const float* lb_v = (const float*)d_in[20];
    const int*   wi_o = (const int*)d_in[21];
    const float* sc_o = (const float*)d_in[22];
    const float* b_o  = (const float*)d_in[23];
    const float* la_o = (const float*)d_in[24];
    const float* lb_o = (const float*)d_in[25];
    const int*   wi_g = (const int*)d_in[26];
    const float* sc_g = (const float*)d_in[27];
    const float* b_g  = (const float*)d_in[28];
    const float* la_g = (const float*)d_in[29];
    const float* lb_g = (const float*)d_in[30];
    const int*   wi_u = (const int*)d_in[31];
    const float* sc_u = (const float*)d_in[32];
    const float* b_u  = (const float*)d_in[33];
    const float* la_u = (const float*)d_in[34];
    const float* lb_u = (const float*)d_in[35];
    const int*   wi_d = (const int*)d_in[36];
    const float* sc_d = (const float*)d_in[37];
    const float* b_d  = (const float*)d_in[38];
    const float* la_d = (const float*)d_in[39];
    const float* lb_d = (const float*)d_in[40];

    float* F    = (float*)d_ws;
    float* XN1  = F + WS_XN1;
    float* Q    = F + WS_Q;
    float* K    = F + WS_KB;
    float* V    = F + WS_VB;
    float* O    = F + WS_OB;
    float* XMED = F + WS_XMED;
    float* XN2  = F + WS_XN2;
    float* PROBS= F + WS_PROBS;
    float* GATE = F + B_GATE;
    float* UP   = F + B_UP;
    float* HAD  = F + B_HAD;
    float* CAND = F + CAND_OFF;
    unsigned* CMX   = (unsigned*)(F + CM_X);
    unsigned* CMXN1 = (unsigned*)(F + CM_XN1);
    unsigned* CMQ   = (unsigned*)(F + CM_Qb);
    unsigned* CMK   = (unsigned*)(F + CM_Kb);
    unsigned* CMV   = (unsigned*)(F + CM_Vb);
    unsigned* CMO   = (unsigned*)(F + CM_Ob);
    unsigned* CMXM  = (unsigned*)(F + CM_XM);
    unsigned* CMXN2 = (unsigned*)(F + CM_XN2b);
    unsigned* CMG   = (unsigned*)(F + CM_GATE);
    unsigned* CMF   = (unsigned*)(F + CM_FN);
    unsigned* CMU   = (unsigned*)(F + CM_UPb);
    unsigned* CMH   = (unsigned*)(F + CM_HAD);
    int*      IDX0  = (int*)(F + WS_IDX);
    int*      IDX1  = IDX0 + 20;
    unsigned* HIST  = (unsigned*)(F + WS_HIST);
    unsigned* SEL   = (unsigned*)(F + WS_SEL);
    float*    RES   = F + WS_RES;
    float*    OUT   = (float*)d_out;
    #define US(off) ((unsigned short*)(F + (off)))

    // 0. zero column-max accumulators
    zero_kernel<<<(CM_TOTAL + 255) / 256, 256, 0, stream>>>(CMX, CM_TOTAL);

    // 1. rmsnorm1 + x channel pack; weights q/k/v -> bf16 (phase A)
    rmsnorm_kernel<<<1024, 256, 0, stream>>>(x, w1, XN1);
    colabsmax_kernel<<<dim3(8, 64), 256, 0, stream>>>(x, 1024, 2048, CMX);
    topk20_kernel<<<1, 256, 0, stream>>>(CMX, OUT + O_XIDX, IDX0);
    packscale_kernel<<<8, 256, 0, stream>>>(CMX, IDX0, OUT + O_XSC, 2048);
    colabsmax_kernel<<<dim3(8, 64), 256, 0, stream>>>(XN1, 1024, 2048, CMXN1);
    w2bf_kernel<<<4096, 256, 0, stream>>>(wi_q, US(A_WQ), 1048576);
    w2bf_kernel<<<1024, 256, 0, stream>>>(wi_k, US(A_WK), 262144);
    w2bf_kernel<<<1024, 256, 0, stream>>>(wi_v, US(A_WV), 262144);

    // 2. q/k/v fused split-K MFMA GEMM
    hilo_kernel<<<2048, 256, 0, stream>>>(XN1, US(A_XN1H), US(A_XN1L), 524288);
    lora_xa_multi_kernel<<<1024, 256, 0, stream>>>(XN1, 2048, 3,
        la_q, US(A_XAQH), US(A_XAQL), la_k, US(A_XAKH), US(A_XAKL), la_v, US(A_XAVH), US(A_XAVL));
    lbt_kernel<<<8, 256, 0, stream>>>(lb_q, sc_q, US(A_LBTQ), 2048);
    lbt_kernel<<<2, 256, 0, stream>>>(lb_k, sc_k, US(A_LBTK), 512);
    lbt_kernel<<<2, 256, 0, stream>>>(lb_v, sc_v, US(A_LBTV), 512);
    zero_kernel<<<12288, 256, 0, stream>>>((unsigned*)Q, 3145728);   // Q,K,V contiguous
    {
        Seg sq{US(A_WQ), US(A_XAQH), US(A_XAQL), US(A_LBTQ), sc_q, b_q, nullptr, Q, 2048, 0};
        Seg sk{US(A_WK), US(A_XAKH), US(A_XAKL), US(A_LBTK), sc_k, b_k, nullptr, K, 512, 16};
        Seg sv{US(A_WV), US(A_XAVH), US(A_XAVL), US(A_LBTV), sc_v, b_v, nullptr, V, 512, 20};
        gemm_mfma3_kernel<<<dim3(24, 8, 2), 256, 0, stream>>>(US(A_XN1H), US(A_XN1L), 2048, 1024, 2, 16, 20, sq, sk, sv);
    }

    // 3. rope (emits bf16 hi/lo) + scales + V transpose
    rope_kernel<<<4096, 256, 0, stream>>>(Q, US(AT_QHG), US(AT_QLG), cosp, sinp, 32);
    rope_kernel<<<1024, 256, 0, stream>>>(K, US(AT_KHG), US(AT_KLG), cosp, sinp, 8);
    colabsmax_kernel<<<dim3(1, 256), 256, 0, stream>>>(Q, 32768, 64, CMQ);
    colabsmax_kernel<<<dim3(1, 128), 256, 0, stream>>>(K, 8192, 64, CMK);
    vtrans_kernel<<<dim3(16, 8), 256, 0, stream>>>(V, US(AT_VTH), US(AT_VTL), CMV);

    // 4. attention (MFMA)
    score_mfma_kernel<<<dim3(36, 32), 256, 0, stream>>>(US(AT_QHG), US(AT_QLG), US(AT_KHG), US(AT_KLG), PROBS);
    softmax_kernel<<<32768, 256, 0, stream>>>(PROBS);
    av_mfma_kernel<<<dim3(16, 32), 256, 0, stream>>>(PROBS, US(AT_VTH), US(AT_VTL), O);
    colabsmax_kernel<<<dim3(8, 64), 256, 0, stream>>>(O, 1024, 2048, CMO);

    // 5. a_thr: ranks 31876709/31876710 of 33554432, frac 0.45
    const long NP = 33554432L;
    sel_init_kernel<<<16, 256, 0, stream>>>(SEL, HIST, 31876709u, 31876710u);
    hist_pass_kernel<<<4096, 256, 0, stream>>>(PROBS, NP, nullptr, 0, SEL + 0, HIST, 20, 0x00000000u);
    resolve_pass_kernel<<<1, 256, 0, stream>>>(SEL + 0, HIST, 20, 0, RES, 0, 0);
    resolve_pass_kernel<<<1, 256, 0, stream>>>(SEL + 2, HIST, 20, 0, RES, 1, 1);
    compact_kernel<<<4096, 256, 0, stream>>>(PROBS, NP, SEL + 0, SEL + 2, CAND, SEL + 4, CAP_CAND);
    hist_pass_kernel<<<256, 256, 0, stream>>>(CAND, 0, SEL + 4, CAP_CAND, SEL + 0, HIST, 8, 0xFFF00000u);
    resolve_pass_kernel<<<1, 256, 0, stream>>>(SEL + 0, HIST, 8, 0, RES, 0, 1);
    hist_pass_kernel<<<256, 256, 0, stream>>>(CAND, 0, SEL + 4, CAP_CAND, SEL + 2, HIST, 8, 0xFFF00000u);
    resolve_pass_kernel<<<1, 256, 0, stream>>>(SEL + 2, HIST, 8, 0, RES, 1, 1);
    hist_pass_kernel<<<256, 256, 0, stream>>>(CAND, 0, SEL + 4, CAP_CAND, SEL + 0, HIST, 0, 0xFFFFFF00u);
    resolve_pass_kernel<<<1, 256, 0, stream>>>(SEL + 0, HIST, 0, 1, RES, 0, 1);
    hist_pass_kernel<<<256, 256, 0, stream>>>(CAND, 0, SEL + 4, CAP_CAND, SEL + 2, HIST, 0, 0xFFFFFF00u);
    resolve_pass_kernel<<<1, 256, 0, stream>>>(SEL + 2, HIST, 0, 1, RES, 1, 1);
    finalize_thr_kernel<<<1, 64, 0, stream>>>(RES, OUT + O_ATHR);

    // 6. o projection (split-K x4, +residual x) -> x_med; pack; rmsnorm2
    w2bf_kernel<<<4096, 256, 0, stream>>>(wi_o, US(B_WO), 1048576);
    hilo_kernel<<<2048, 256, 0, stream>>>(O, US(B_OH), US(B_OL), 524288);
    lora_xa_multi_kernel<<<1024, 256, 0, stream>>>(O, 2048, 1,
        la_o, US(B_XAOH), US(B_XAOL), nullptr, nullptr, nullptr, nullptr, nullptr, nullptr);
    lbt_kernel<<<8, 256, 0, stream>>>(lb_o, sc_o, US(B_LBTO), 2048);
    zero_kernel<<<8192, 256, 0, stream>>>((unsigned*)XMED, 2097152);
    {
        Seg so{US(B_WO), US(B_XAOH), US(B_XAOL), US(B_LBTO), sc_o, b_o, x, XMED, 2048, 0};
        gemm_mfma3_kernel<<<dim3(16, 8, 4), 256, 0, stream>>>(US(B_OH), US(B_OL), 2048, 512, 4, 999, 999, so, so, so);
    }
    colabsmax_kernel<<<dim3(8, 64), 256, 0, stream>>>(XMED, 1024, 2048, CMXM);
    topk20_kernel<<<1, 256, 0, stream>>>(CMXM, OUT + O_XMIDX, IDX1);
    packscale_kernel<<<8, 256, 0, stream>>>(CMXM, IDX1, OUT + O_XMS, 2048);
    rmsnorm_kernel<<<1024, 256, 0, stream>>>(XMED, w2, XN2);
    colabsmax_kernel<<<dim3(8, 64), 256, 0, stream>>>(XN2, 1024, 2048, CMXN2);

    // 7. MLP: gate+up fused GEMM, fused silu/hadamard + 4 col-maxes
    w2bf_kernel<<<11264, 256, 0, stream>>>(wi_g, US(B_WG), 2883584);
    w2bf_kernel<<<11264, 256, 0, stream>>>(wi_u, US(B_WU), 2883584);
    hilo_kernel<<<2048, 256, 0, stream>>>(XN2, US(B_XN2H), US(B_XN2L), 524288);
    lora_xa_multi_kernel<<<1024, 256, 0, stream>>>(XN2, 2048, 2,
        la_g, US(B_XAGH), US(B_XAGL), la_u, US(B_XAUH), US(B_XAUL), nullptr, nullptr, nullptr);
    lbt_kernel<<<22, 256, 0, stream>>>(lb_g, sc_g, US(B_LBTG), 5632);
    lbt_kernel<<<22, 256, 0, stream>>>(lb_u, sc_u, US(B_LBTU), 5632);
    {
        Seg sg{US(B_WG), US(B_XAGH), US(B_XAGL), US(B_LBTG), sc_g, b_g, nullptr, GATE, 5632, 0};
        Seg su{US(B_WU), US(B_XAUH), US(B_XAUL), US(B_LBTU), sc_u, b_u, nullptr, UP, 5632, 44};
        gemm_mfma3_kernel<<<dim3(88, 8, 1), 256, 0, stream>>>(US(B_XN2H), US(B_XN2L), 2048, 2048, 1, 44, 88, sg, su, su);
    }
    w2bf_kernel<<<11264, 256, 0, stream>>>(wi_d, US(B_WD), 2883584);
    hadfuse_kernel<<<dim3(22, 32), 256, 0, stream>>>(GATE, UP, HAD, CMG, CMF, CMU, CMH);

    // 8. down projection (split-K x4, +residual x_med) -> x_out
    hilo_kernel<<<5632, 256, 0, stream>>>(HAD, US(B_HADH), US(B_HADL), 1441792);
    lora_xa_multi_kernel<<<1024, 256, 0, stream>>>(HAD, 5632, 1,
        la_d, US(B_XADH), US(B_XADL), nullptr, nullptr, nullptr, nullptr, nullptr, nullptr);
    lbt_kernel<<<8, 256, 0, stream>>>(lb_d, sc_d, US(B_LBTD), 2048);
    zero_kernel<<<8192, 256, 0, stream>>>((unsigned*)(OUT + O_XOUT), 2097152);
    {
        Seg sd{US(B_WD), US(B_XADH), US(B_XADL), US(B_LBTD), sc_d, b_d, XMED, OUT + O_XOUT, 2048, 0};
        gemm_mfma3_kernel<<<dim3(16, 8, 4), 256, 0, stream>>>(US(B_HADH), US(B_HADL), 5632, 1408, 4, 999, 999, sd, sd, sd);
    }

    // 9. all act_quant scales in one pass
    scale_fin_all_kernel<<<113, 256, 0, stream>>>((const unsigned*)(F + WS_SMALL), OUT);
    #undef US
}

// Round 7
// 1225.989 us; speedup vs baseline: 2.6207x; 1.1914x over previous
//
#include <hip/hip_runtime.h>

// ---------------- problem dims ----------------
// B=1, S=1024, C=2048, H=32, D=64, HKV=8, R=16, FF=5632, Q_BIT=4 (qmax=7)

// ---------------- ws layout (float offsets) ----------------
#define WS_XN1   0L            // also QHG/QLG (bf16) after qkv
#define WS_Q     2097152L      // Q/K/V fp32; dead after step 3 -> CAND (step 5) / XA32 (steps 2,6,7,8)
#define WS_KB    4194304L
#define WS_VB    4718592L
#define WS_OB    5242880L
#define WS_XMED  7340032L      // also KHG/KLG/VTH/VTL (bf16) during attention
#define WS_XN2   9437184L
#define WS_PROBS 11534336L     // 33554432 floats
// ---- phase A aliases (inside probs; dead before score writes probs) ----
#define PA        WS_PROBS
#define A_WQ      (PA + 0L)
#define A_WK      (PA + 2097152L)
#define A_WV      (PA + 2621440L)
#define A_XN1H    (PA + 3145728L)
#define A_XN1L    (PA + 4194304L)
#define A_XAQH    (PA + 5242880L)
#define A_XAQL    (PA + 5259264L)
#define A_XAKH    (PA + 5275648L)
#define A_XAKL    (PA + 5292032L)
#define A_XAVH    (PA + 5308416L)
#define A_XAVL    (PA + 5324800L)
#define A_LBTQ    (PA + 5341184L)
#define A_LBTK    (PA + 5373952L)
#define A_LBTV    (PA + 5382144L)
// ---- attention bf16 aliases (outside probs) ----
#define AT_QHG    (WS_XN1 + 0L)        // 1024x2048 bf16
#define AT_QLG    (WS_XN1 + 1048576L)
#define AT_KHG    (WS_XMED + 0L)       // 1024x512 bf16
#define AT_KLG    (WS_XMED + 262144L)
#define AT_VTH    (WS_XMED + 524288L)  // 8x64x1024 bf16
#define AT_VTL    (WS_XMED + 786432L)
#define CAND_OFF  WS_Q                 // quantile candidates (Q/K/V fp32 region, dead)
#define CAP_CAND  3145728u
#define XA32_OFF  WS_Q                 // fp32 lora xa accumulators [nset<=3][1024][16]
// ---- phase B aliases (inside probs; written only after quantile) ----
#define B_WO      (PA + 0L)
#define B_OH      (PA + 2097152L)
#define B_OL      (PA + 3145728L)
#define B_XAOH    (PA + 4194304L)
#define B_XAOL    (PA + 4210688L)
#define B_LBTO    (PA + 4227072L)
#define B_WG      (PA + 4300800L)
#define B_WU      (PA + 10067968L)
#define B_XN2H    (PA + 15835136L)
#define B_XN2L    (PA + 16883712L)
#define B_XAGH    (PA + 17932288L)
#define B_XAGL    (PA + 17948672L)
#define B_XAUH    (PA + 17965056L)
#define B_XAUL    (PA + 17981440L)
#define B_LBTG    (PA + 17997824L)
#define B_LBTU    (PA + 18087936L)
#define B_GATE    (PA + 18178048L)
#define B_UP      (PA + 23945216L)
#define B_HAD     (PA + 4300800L)      // WG slot
#define B_WD      (PA + 10067968L)     // WU slot
#define B_HADH    (PA + 0L)            // WO+OH slots
#define B_HADL    (PA + 18178048L)     // GATE slot
#define B_XADH    (PA + 15835136L)
#define B_XADL    (PA + 15851520L)
#define B_LBTD    (PA + 15867904L)
// ---- small stuff ----
#define WS_SMALL 45088768L
#define CM_X     (WS_SMALL + 0L)
#define CM_XN1   (WS_SMALL + 2048L)
#define CM_Qb    (WS_SMALL + 4096L)
#define CM_Kb    (WS_SMALL + 4160L)
#define CM_Vb    (WS_SMALL + 4224L)
#define CM_Ob    (WS_SMALL + 4288L)
#define CM_XM    (WS_SMALL + 6336L)
#define CM_XN2b  (WS_SMALL + 8384L)
#define CM_GATE  (WS_SMALL + 10432L)
#define CM_FN    (WS_SMALL + 16064L)
#define CM_UPb   (WS_SMALL + 21696L)
#define CM_HAD   (WS_SMALL + 27328L)
#define CM_TOTAL 32960
#define WS_IDX   (WS_SMALL + 32960L)
#define WS_HIST  (WS_IDX + 64L)
#define WS_SEL   (WS_HIST + 4096L)
#define WS_RES   (WS_SEL + 8L)

// ---------------- out layout (float offsets) ----------------
#define O_XOUT  0L
#define O_XIDX  2097152L
#define O_XSC   2097172L
#define O_XN1S  2099220L
#define O_QS    2101268L
#define O_KS    2101332L
#define O_VS    2101396L
#define O_ATHR  2101460L
#define O_OS    2101461L
#define O_XMIDX 2103509L
#define O_XMS   2103529L
#define O_XN2S  2105577L
#define O_GATES 2107625L
#define O_UPS   2113257L
#define O_FNS   2118889L
#define O_HADS  2124521L

typedef float  floatx4 __attribute__((ext_vector_type(4)));
typedef short  shortx8 __attribute__((ext_vector_type(8)));

static __device__ __forceinline__ unsigned short f2bf(float f) {
    unsigned u = __float_as_uint(f);
    return (unsigned short)((u + 0x7FFFu + ((u >> 16) & 1u)) >> 16);
}
static __device__ __forceinline__ float bf2f(unsigned short b) {
    return __uint_as_float(((unsigned)b) << 16);
}
static __device__ __forceinline__ void gload_lds16(const void* g, void* l) {
    __builtin_amdgcn_global_load_lds(
        (const __attribute__((address_space(1))) unsigned int*)g,
        (__attribute__((address_space(3))) unsigned int*)l, 16, 0, 0);
}
static __device__ __forceinline__ void cvt8(const float4 a, const float4 b,
                                            shortx8& h8, shortx8& l8) {
    float v[8] = {a.x, a.y, a.z, a.w, b.x, b.y, b.z, b.w};
#pragma unroll
    for (int i = 0; i < 8; i++) {
        unsigned short h = f2bf(v[i]);
        h8[i] = (short)h;
        l8[i] = (short)f2bf(v[i] - bf2f(h));
    }
}

// ---------------- small utility kernels ----------------
__global__ void zero_kernel(unsigned* __restrict__ p, int n) {
    int i = blockIdx.x * 256 + threadIdx.x;
    if (i < n) p[i] = 0u;
}

__global__ __launch_bounds__(256) void rmsnorm_kernel(const float* __restrict__ x,
                                                      const float* __restrict__ w,
                                                      float* __restrict__ out) {
    const int row = blockIdx.x;
    const int tid = threadIdx.x;
    const float* xr = x + row * 2048;
    float s = 0.f;
    for (int i = tid; i < 2048; i += 256) { float v = xr[i]; s += v * v; }
    __shared__ float red[256];
    red[tid] = s; __syncthreads();
    for (int off = 128; off; off >>= 1) { if (tid < off) red[tid] += red[tid + off]; __syncthreads(); }
    const float rstd = 1.0f / sqrtf(red[0] / 2048.0f + 1e-5f);
    float* orow = out + row * 2048;
    for (int i = tid; i < 2048; i += 256) orow[i] = xr[i] * rstd * w[i];
}

__global__ void colabsmax_kernel(const float* __restrict__ in, int M, int N,
                                 unsigned* __restrict__ outb) {
    const int c = blockIdx.x * 256 + threadIdx.x;
    if (c >= N) return;
    float loc = 0.f;
    for (int r = blockIdx.y; r < M; r += gridDim.y)
        loc = fmaxf(loc, fabsf(in[(long)r * N + c]));
    atomicMax(outb + c, __float_as_uint(loc));
}

__global__ __launch_bounds__(256) void scale_fin_all_kernel(const unsigned* __restrict__ cm,
                                                            float* __restrict__ OUT) {
    int i = blockIdx.x * 256 + threadIdx.x;
    const int  n[10]  = {2048, 64, 64, 64, 2048, 2048, 5632, 5632, 5632, 5632};
    const int  co[10] = {2048, 4096, 4160, 4224, 4288, 8384, 10432, 16064, 21696, 27328};
    const long oo[10] = {O_XN1S, O_QS, O_KS, O_VS, O_OS, O_XN2S, O_GATES, O_FNS, O_UPS, O_HADS};
#pragma unroll
    for (int s = 0; s < 10; s++) {
        if (i < n[s]) { OUT[oo[s] + i] = __uint_as_float(cm[co[s] + i]) / 7.0f + 1e-8f; return; }
        i -= n[s];
    }
}

__global__ __launch_bounds__(256) void topk20_kernel(const unsigned* __restrict__ cmaxbits,
                                                     float* __restrict__ out_idx_f,
                                                     int* __restrict__ out_idx_i) {
    __shared__ float vals[2048];
    __shared__ float rv[256];
    __shared__ int   ri[256];
    const int tid = threadIdx.x;
    for (int i = tid; i < 2048; i += 256) vals[i] = __uint_as_float(cmaxbits[i]);
    __syncthreads();
    for (int t = 0; t < 20; t++) {
        float bv = -1.f; int bi = 1 << 30;
        for (int i = tid; i < 2048; i += 256) {
            float v = vals[i];
            if (v > bv) { bv = v; bi = i; }
        }
        rv[tid] = bv; ri[tid] = bi; __syncthreads();
        for (int off = 128; off; off >>= 1) {
            if (tid < off) {
                float v2 = rv[tid + off]; int i2 = ri[tid + off];
                if (v2 > rv[tid] || (v2 == rv[tid] && i2 < ri[tid])) { rv[tid] = v2; ri[tid] = i2; }
            }
            __syncthreads();
        }
        if (tid == 0) { out_idx_f[t] = (float)ri[0]; out_idx_i[t] = ri[0]; vals[ri[0]] = -1.f; }
        __syncthreads();
    }
}

__global__ void packscale_kernel(const unsigned* __restrict__ cmaxbits,
                                 const int* __restrict__ idx, float* __restrict__ out, int n) {
    const int c = blockIdx.x * 256 + threadIdx.x;
    if (c >= n) return;
    bool outl = false;
    for (int t = 0; t < 20; t++) outl |= (idx[t] == c);
    const float m = __uint_as_float(cmaxbits[c]);
    out[c] = outl ? 1e-8f : (m / 7.0f + 1e-8f);
}

// LoRA xa, split-K + ILP-4: grid (M, K/512, nset). Partial sums atomicAdd into
// fp32 xa32[set][M][16]. (Round-6 version: 1024 blocks, dependent-load chain,
// 132 us at VALUBusy=10% -- pure latency stall.)
__global__ __launch_bounds__(256) void lora_xa2_kernel(
    const float* __restrict__ A, int K,
    const float* __restrict__ la0, const float* __restrict__ la1, const float* __restrict__ la2,
    float* __restrict__ xa32)
{
    const int m = blockIdx.x, kc = blockIdx.y, set = blockIdx.z;
    const float* la = (set == 0) ? la0 : (set == 1) ? la1 : la2;
    const int tid = threadIdx.x;
    const int r = tid & 15, g = tid >> 4;
    const int k0 = kc * 512;
    const float* Am = A + (size_t)m * K + k0;
    const float* lap = la + (size_t)k0 * 16 + r;
    float a0 = 0.f, a1 = 0.f, a2 = 0.f, a3 = 0.f;
#pragma unroll
    for (int i = 0; i < 32; i += 4) {
        const int kA = g + 16 * i;
        const float x0 = Am[kA];      const float y0 = lap[(size_t)(kA) * 16];
        const float x1 = Am[kA + 16]; const float y1 = lap[(size_t)(kA + 16) * 16];
        const float x2 = Am[kA + 32]; const float y2 = lap[(size_t)(kA + 32) * 16];
        const float x3 = Am[kA + 48]; const float y3 = lap[(size_t)(kA + 48) * 16];
        a0 += x0 * y0; a1 += x1 * y1; a2 += x2 * y2; a3 += x3 * y3;
    }
    float s = (a0 + a1) + (a2 + a3);
    __shared__ float red[256];
    red[tid] = s; __syncthreads();
    for (int off = 128; off >= 16; off >>= 1) { if (tid < off) red[tid] += red[tid + off]; __syncthreads(); }
    if (tid < 16) atomicAdd(&xa32[((size_t)set * 1024 + m) * 16 + tid], red[tid]);
}

// xa32 fp32 -> padded bf16 hi/lo [M][32]
__global__ void xa_cvt_kernel(const float* __restrict__ xa32,
                              unsigned short* __restrict__ xh0, unsigned short* __restrict__ xl0,
                              unsigned short* __restrict__ xh1, unsigned short* __restrict__ xl1,
                              unsigned short* __restrict__ xh2, unsigned short* __restrict__ xl2) {
    const int i = blockIdx.x * 256 + threadIdx.x;   // 0..32767
    const int set = blockIdx.y;
    unsigned short* xh = (set == 0) ? xh0 : (set == 1) ? xh1 : xh2;
    unsigned short* xl = (set == 0) ? xl0 : (set == 1) ? xl1 : xl2;
    const int m = i >> 5, j = i & 31;
    if (j < 16) {
        const float v = xa32[((size_t)set * 1024 + m) * 16 + j];
        const unsigned short h = f2bf(v);
        xh[m * 32 + j] = h; xl[m * 32 + j] = f2bf(v - bf2f(h));
    } else {
        xh[m * 32 + j] = 0; xl[m * 32 + j] = 0;
    }
}

__global__ void hilo_kernel(const float* __restrict__ in, unsigned short* __restrict__ hi,
                            unsigned short* __restrict__ lo, long n4) {
    const long i = (long)blockIdx.x * 256 + threadIdx.x;
    if (i >= n4) return;
    const float4 v = *(const float4*)(in + i * 4);
    ushort4 h, l;
    h.x = f2bf(v.x); l.x = f2bf(v.x - bf2f(h.x));
    h.y = f2bf(v.y); l.y = f2bf(v.y - bf2f(h.y));
    h.z = f2bf(v.z); l.z = f2bf(v.z - bf2f(h.z));
    h.w = f2bf(v.w); l.w = f2bf(v.w - bf2f(h.w));
    *(ushort4*)(hi + i * 4) = h;
    *(ushort4*)(lo + i * 4) = l;
}

__global__ void w2bf_kernel(const int* __restrict__ wi, unsigned short* __restrict__ out, long n4) {
    const long i = (long)blockIdx.x * 256 + threadIdx.x;
    if (i >= n4) return;
    const int4 w = *(const int4*)(wi + i * 4);
    ushort4 o;
    o.x = (unsigned short)(__float_as_uint((float)w.x) >> 16);
    o.y = (unsigned short)(__float_as_uint((float)w.y) >> 16);
    o.z = (unsigned short)(__float_as_uint((float)w.z) >> 16);
    o.w = (unsigned short)(__float_as_uint((float)w.w) >> 16);
    *(ushort4*)(out + i * 4) = o;
}

__global__ void lbt_kernel(const float* __restrict__ lb, const float* __restrict__ sc,
                           unsigned short* __restrict__ out, int N) {
    const int n = blockIdx.x * 256 + threadIdx.x;
    if (n >= N) return;
    const float inv = 1.0f / sc[n];
    for (int r = 0; r < 16; r++) out[n * 32 + r] = f2bf(lb[r * N + n] * inv);
    for (int r = 16; r < 32; r++) out[n * 32 + r] = 0;
}

// rope in-place + emit bf16 hi/lo copies
__global__ void rope_kernel(float* __restrict__ x, unsigned short* __restrict__ xh,
                            unsigned short* __restrict__ xl,
                            const float* __restrict__ cs, const float* __restrict__ sn, int nh) {
    const int idx = blockIdx.x * 256 + threadIdx.x;
    const int tot = 1024 * nh * 32;
    if (idx >= tot) return;
    const int d = idx & 31;
    const int h = (idx >> 5) % nh;
    const int s = (idx >> 5) / nh;
    const long e = (long)s * (nh * 64) + h * 64 + d;
    const float x1 = x[e], x2 = x[e + 32];
    const float c1 = cs[s * 64 + d],      s1 = sn[s * 64 + d];
    const float c2 = cs[s * 64 + d + 32], s2 = sn[s * 64 + d + 32];
    const float v1 = x1 * c1 - x2 * s1;
    const float v2 = x2 * c2 + x1 * s2;
    x[e] = v1; x[e + 32] = v2;
    unsigned short h1 = f2bf(v1), h2 = f2bf(v2);
    xh[e] = h1;      xl[e] = f2bf(v1 - bf2f(h1));
    xh[e + 32] = h2; xl[e + 32] = f2bf(v2 - bf2f(h2));
}

// V -> VT (bf16 hi/lo, [kvh][64 d][1024 s]) + per-d abs-max
__global__ __launch_bounds__(256) void vtrans_kernel(const float* __restrict__ V,
                                                     unsigned short* __restrict__ vth,
                                                     unsigned short* __restrict__ vtl,
                                                     unsigned* __restrict__ cmv) {
    __shared__ float T[64][65];
    __shared__ unsigned vmax[64];
    const int st = blockIdx.x, h = blockIdx.y, t = threadIdx.x;
    if (t < 64) vmax[t] = 0u;
    const int r = t >> 2, cb = (t & 3) * 16;
    const float* src = V + (size_t)(st * 64 + r) * 512 + h * 64 + cb;
#pragma unroll
    for (int i = 0; i < 4; i++) {
        const float4 v = *(const float4*)(src + i * 4);
        T[r][cb + i * 4 + 0] = v.x; T[r][cb + i * 4 + 1] = v.y;
        T[r][cb + i * 4 + 2] = v.z; T[r][cb + i * 4 + 3] = v.w;
    }
    __syncthreads();
    const int dd = t >> 2, sb = (t & 3) * 16;
    shortx8 th0, th1, tl0, tl1;
    float mx = 0.f;
#pragma unroll
    for (int i = 0; i < 16; i++) {
        const float f = T[sb + i][dd];
        mx = fmaxf(mx, fabsf(f));
        const unsigned short hh = f2bf(f);
        const unsigned short ll = f2bf(f - bf2f(hh));
        if (i < 8) { th0[i] = (short)hh; tl0[i] = (short)ll; }
        else       { th1[i - 8] = (short)hh; tl1[i - 8] = (short)ll; }
    }
    atomicMax(&vmax[dd], __float_as_uint(mx));
    const size_t off = (size_t)(h * 64 + dd) * 1024 + st * 64 + sb;
    *(shortx8*)&vth[off] = th0; *(shortx8*)&vth[off + 8] = th1;
    *(shortx8*)&vtl[off] = tl0; *(shortx8*)&vtl[off + 8] = tl1;
    __syncthreads();
    if (t < 64) atomicMax(cmv + t, vmax[t]);
}

// gate/up -> had + 4 column abs-maxes
__global__ __launch_bounds__(256) void hadfuse_kernel(const float* __restrict__ gate,
                                                      const float* __restrict__ up,
                                                      float* __restrict__ had,
                                                      unsigned* __restrict__ cmg, unsigned* __restrict__ cmf,
                                                      unsigned* __restrict__ cmu, unsigned* __restrict__ cmh) {
    const int c = blockIdx.x * 256 + threadIdx.x;
    if (c >= 5632) return;
    float mg = 0.f, mf = 0.f, mu = 0.f, mh = 0.f;
    for (int r = blockIdx.y; r < 1024; r += gridDim.y) {
        const float g = gate[(long)r * 5632 + c];
        const float u = up[(long)r * 5632 + c];
        const float fn = g / (1.f + expf(-g));
        const float hv = u * fn;
        had[(long)r * 5632 + c] = hv;
        mg = fmaxf(mg, fabsf(g)); mf = fmaxf(mf, fabsf(fn));
        mu = fmaxf(mu, fabsf(u)); mh = fmaxf(mh, fabsf(hv));
    }
    atomicMax(cmg + c, __float_as_uint(mg));
    atomicMax(cmf + c, __float_as_uint(mf));
    atomicMax(cmu + c, __float_as_uint(mu));
    atomicMax(cmh + c, __float_as_uint(mh));
}

// ---------------- MFMA GEMM with split-K ----------------
struct Seg {
    const unsigned short *W, *xh, *xl, *lbt;
    const float *sc, *b, *res;
    float *C;
    int N;
    int bx0;
};

__global__ __launch_bounds__(256) void gemm_mfma3_kernel(
    const unsigned short* __restrict__ Ah, const unsigned short* __restrict__ Al,
    int K, int Kc, int KS, int c1, int c2, Seg s0, Seg s1, Seg s2)
{
    __shared__ unsigned short lds[2][3][4096];   // dbuf x {AH, AL, B} x 8KB
    const int tid  = threadIdx.x;
    const int wave = tid >> 6, lane = tid & 63;
    const Seg s = (blockIdx.x < c1) ? s0 : (blockIdx.x < c2) ? s1 : s2;
    const int bn = (blockIdx.x - s.bx0) * 128;
    const int bm = blockIdx.y * 128;
    const int z  = blockIdx.z;
    const int wm = (wave >> 1) * 64, wn = (wave & 1) * 64;
    const int l15 = lane & 15, l4 = lane >> 4;
    const int qe = (l4 ^ ((l15 >> 1) & 3)) * 8;
    const int lrow = lane >> 2;
    const int csrc = (lane & 3) ^ ((lane >> 3) & 3);
    const size_t strideMain = (size_t)K * 2;
    const int iters = Kc >> 5;
    const int nsteps = iters + (z == 0 ? 1 : 0);

    floatx4 acc[4][4];
#pragma unroll
    for (int i = 0; i < 4; i++)
#pragma unroll
        for (int j = 0; j < 4; j++) acc[i][j] = (floatx4){0.f, 0.f, 0.f, 0.f};

    auto load3 = [&](int it, int buf) {
        const char *pAh, *pAl, *pB; size_t stA, stB, kb;
        if (it < iters) {
            pAh = (const char*)Ah; pAl = (const char*)Al; pB = (const char*)s.W;
            stA = strideMain; stB = strideMain; kb = (size_t)(z * Kc + it * 32) * 2;
        } else {
            pAh = (const char*)s.xh; pAl = (const char*)s.xl; pB = (const char*)s.lbt;
            stA = 64; stB = 64; kb = 0;
        }
#pragma unroll
        for (int issue = 0; issue < 2; issue++) {
            const int rt = wave * 32 + issue * 16 + lrow;
            const size_t co = kb + (size_t)csrc * 16;
            unsigned short* d0 = &lds[buf][0][(wave * 32 + issue * 16) * 32];
            unsigned short* d1 = &lds[buf][1][(wave * 32 + issue * 16) * 32];
            unsigned short* d2 = &lds[buf][2][(wave * 32 + issue * 16) * 32];
            gload_lds16(pAh + (size_t)(bm + rt) * stA + co, d0);
            gload_lds16(pAl + (size_t)(bm + rt) * stA + co, d1);
            gload_lds16(pB  + (size_t)(bn + rt) * stB + co, d2);
        }
    };

    load3(0, 0);
    for (int it = 0; it < nsteps; it++) {
        const int cur = it & 1;
        __syncthreads();
        if (it + 1 < nsteps) load3(it + 1, cur ^ 1);
        const unsigned short* tAh = lds[cur][0];
        const unsigned short* tAl = lds[cur][1];
        const unsigned short* tB  = lds[cur][2];
        shortx8 afh[4], afl[4], bfr[4];
#pragma unroll
        for (int i = 0; i < 4; i++) {
            afh[i] = *(const shortx8*)&tAh[(wm + i * 16 + l15) * 32 + qe];
            afl[i] = *(const shortx8*)&tAl[(wm + i * 16 + l15) * 32 + qe];
            bfr[i] = *(const shortx8*)&tB [(wn + i * 16 + l15) * 32 + qe];
        }
#pragma unroll
        for (int i = 0; i < 4; i++)
#pragma unroll
            for (int j = 0; j < 4; j++) {
                acc[i][j] = __builtin_amdgcn_mfma_f32_16x16x32_bf16(afh[i], bfr[j], acc[i][j], 0, 0, 0);
                acc[i][j] = __builtin_amdgcn_mfma_f32_16x16x32_bf16(afl[i], bfr[j], acc[i][j], 0, 0, 0);
            }
    }

#pragma unroll
    for (int j = 0; j < 4; j++) {
        const int n = bn + wn + j * 16 + l15;
        const float scn = s.sc[n];
        const float bsn = (z == 0) ? s.b[n] : 0.f;
#pragma unroll
        for (int i = 0; i < 4; i++) {
            const int m0 = bm + wm + i * 16 + l4 * 4;
#pragma unroll
            for (int r = 0; r < 4; r++) {
                const int m = m0 + r;
                float v = acc[i][j][r] * scn + bsn;
                if (z == 0 && s.res) v += s.res[(size_t)m * s.N + n];
                if (KS == 1) s.C[(size_t)m * s.N + n] = v;
                else atomicAdd(&s.C[(size_t)m * s.N + n], v);
            }
        }
    }
}

// ---------------- attention: MFMA score (lower-triangle 128x128 tiles) ----------------
__global__ __launch_bounds__(256) void score_mfma_kernel(
    const unsigned short* __restrict__ QH, const unsigned short* __restrict__ QL,
    const unsigned short* __restrict__ KH, const unsigned short* __restrict__ KL,
    float* __restrict__ probs)
{
    __shared__ unsigned short q_h[4096], q_l[4096], k_h[4096], k_l[4096];
    const int tid = threadIdx.x, wave = tid >> 6, lane = tid & 63;
    const int t = blockIdx.x, h = blockIdx.y;
    int by = 0;
    while ((by + 1) * (by + 2) / 2 <= t) by++;
    const int bx = t - by * (by + 1) / 2;
    const int wm = (wave >> 1) * 64, wn = (wave & 1) * 64;
    const int l15 = lane & 15, l4 = lane >> 4;
    const int qe = (l4 ^ ((l15 >> 1) & 3)) * 8;
    const int lrow = lane >> 2;
    const int csrc = (lane & 3) ^ ((lane >> 3) & 3);

    floatx4 acc[4][4];
#pragma unroll
    for (int i = 0; i < 4; i++)
#pragma unroll
        for (int j = 0; j < 4; j++) acc[i][j] = (floatx4){0.f, 0.f, 0.f, 0.f};

    for (int s = 0; s < 2; s++) {
        __syncthreads();
#pragma unroll
        for (int issue = 0; issue < 2; issue++) {
            const int rq = by * 128 + wave * 32 + issue * 16 + lrow;
            const int rk = bx * 128 + wave * 32 + issue * 16 + lrow;
            const size_t coq = ((size_t)rq * 2048 + h * 64 + s * 32) * 2 + (size_t)csrc * 16;
            const size_t cok = ((size_t)rk * 512 + (h >> 2) * 64 + s * 32) * 2 + (size_t)csrc * 16;
            const int db = (wave * 32 + issue * 16) * 32;
            gload_lds16((const char*)QH + coq, &q_h[db]);
            gload_lds16((const char*)QL + coq, &q_l[db]);
            gload_lds16((const char*)KH + cok, &k_h[db]);
            gload_lds16((const char*)KL + cok, &k_l[db]);
        }
        __syncthreads();
        shortx8 ah[4], al[4], bh[4], bl[4];
#pragma unroll
        for (int i = 0; i < 4; i++) {
            ah[i] = *(const shortx8*)&q_h[(wm + i * 16 + l15) * 32 + qe];
            al[i] = *(const shortx8*)&q_l[(wm + i * 16 + l15) * 32 + qe];
            bh[i] = *(const shortx8*)&k_h[(wn + i * 16 + l15) * 32 + qe];
            bl[i] = *(const shortx8*)&k_l[(wn + i * 16 + l15) * 32 + qe];
        }
#pragma unroll
        for (int i = 0; i < 4; i++)
#pragma unroll
            for (int j = 0; j < 4; j++) {
                acc[i][j] = __builtin_amdgcn_mfma_f32_16x16x32_bf16(ah[i], bh[j], acc[i][j], 0, 0, 0);
                acc[i][j] = __builtin_amdgcn_mfma_f32_16x16x32_bf16(al[i], bh[j], acc[i][j], 0, 0, 0);
                acc[i][j] = __builtin_amdgcn_mfma_f32_16x16x32_bf16(ah[i], bl[j], acc[i][j], 0, 0, 0);
            }
    }
#pragma unroll
    for (int j = 0; j < 4; j++) {
        const int col = bx * 128 + wn + j * 16 + l15;
#pragma unroll
        for (int i = 0; i < 4; i++) {
#pragma unroll
            for (int r = 0; r < 4; r++) {
                const int row = by * 128 + wm + i * 16 + l4 * 4 + r;
                probs[((size_t)(h * 1024) + row) * 1024 + col] = acc[i][j][r] * 0.125f;
            }
        }
    }
}

__global__ __launch_bounds__(256) void softmax_kernel(float* __restrict__ probs) {
    const int row = blockIdx.x;
    const int qi = row & 1023;
    float* p = probs + (long)row * 1024;
    const int tid = threadIdx.x;
    __shared__ float red[256];
    float m = -3.4e38f;
    for (int i = tid; i <= qi; i += 256) m = fmaxf(m, p[i]);
    red[tid] = m; __syncthreads();
    for (int off = 128; off; off >>= 1) { if (tid < off) red[tid] = fmaxf(red[tid], red[tid + off]); __syncthreads(); }
    m = red[0]; __syncthreads();
    float s = 0.f;
    for (int i = tid; i <= qi; i += 256) { float e = expf(p[i] - m); p[i] = e; s += e; }
    red[tid] = s; __syncthreads();
    for (int off = 128; off; off >>= 1) { if (tid < off) red[tid] += red[tid + off]; __syncthreads(); }
    const float inv = 1.f / red[0];
    for (int i = tid; i < 1024; i += 256) p[i] = (i <= qi) ? p[i] * inv : 0.f;
}

// ---------------- attention: MFMA AV (64-row q tiles) ----------------
__global__ __launch_bounds__(256) void av_mfma_kernel(
    const float* __restrict__ probs,
    const unsigned short* __restrict__ VTH, const unsigned short* __restrict__ VTL,
    float* __restrict__ obuf)
{
    __shared__ unsigned short p_h[4096], p_l[4096];   // [2 sub][64][32]
    __shared__ unsigned short v_h[4096], v_l[4096];
    const int tid = threadIdx.x, wave = tid >> 6, lane = tid & 63;
    const int qt = blockIdx.x, h = blockIdx.y;
    const int wm = (wave >> 1) * 32, wn = (wave & 1) * 32;
    const int l15 = lane & 15, l4 = lane >> 4;
    const int qe = (l4 ^ ((l15 >> 1) & 3)) * 8;
    const int lrow = lane >> 2;
    const int csrc = (lane & 3) ^ ((lane >> 3) & 3);
    const int nch = qt + 1;
    // P conversion constants
    const int pr = tid >> 2, pc = (tid & 3) * 16;
    const int psub = (tid >> 1) & 1, pc0 = (tid & 1) * 2;
    const int pswz = (pr >> 1) & 3;

    floatx4 acc[2][2];
#pragma unroll
    for (int i = 0; i < 2; i++)
#pragma unroll
        for (int j = 0; j < 2; j++) acc[i][j] = (floatx4){0.f, 0.f, 0.f, 0.f};

    for (int kc = 0; kc < nch; kc++) {
        __syncthreads();
        // VT via global_load_lds: per wave 16 d-rows, 2 k-subs. VT is indexed by KV head (h>>2)!
#pragma unroll
        for (int sb = 0; sb < 2; sb++) {
            const size_t off = ((size_t)((h >> 2) * 64 + wave * 16 + lrow) * 1024 + kc * 64 + sb * 32) * 2
                               + (size_t)csrc * 16;
            gload_lds16((const char*)VTH + off, &v_h[sb * 2048 + wave * 16 * 32]);
            gload_lds16((const char*)VTL + off, &v_l[sb * 2048 + wave * 16 * 32]);
        }
        // P fp32 -> bf16 hi/lo into LDS
        const float* Prow = probs + ((size_t)(h * 1024) + qt * 64 + pr) * 1024 + kc * 64 + pc;
        const float4 f0 = *(const float4*)(Prow + 0);
        const float4 f1 = *(const float4*)(Prow + 4);
        const float4 f2 = *(const float4*)(Prow + 8);
        const float4 f3 = *(const float4*)(Prow + 12);
        shortx8 h0, l0, h1, l1;
        cvt8(f0, f1, h0, l0);
        cvt8(f2, f3, h1, l1);
        const int st0 = pc0 ^ pswz, st1 = (pc0 + 1) ^ pswz;
        *(shortx8*)&p_h[psub * 2048 + pr * 32 + st0 * 8] = h0;
        *(shortx8*)&p_h[psub * 2048 + pr * 32 + st1 * 8] = h1;
        *(shortx8*)&p_l[psub * 2048 + pr * 32 + st0 * 8] = l0;
        *(shortx8*)&p_l[psub * 2048 + pr * 32 + st1 * 8] = l1;
        __syncthreads();
#pragma unroll
        for (int s = 0; s < 2; s++) {
            shortx8 ah[2], al[2], bh[2], bl[2];
#pragma unroll
            for (int i = 0; i < 2; i++) {
                ah[i] = *(const shortx8*)&p_h[s * 2048 + (wm + i * 16 + l15) * 32 + qe];
                al[i] = *(const shortx8*)&p_l[s * 2048 + (wm + i * 16 + l15) * 32 + qe];
                bh[i] = *(const shortx8*)&v_h[s * 2048 + (wn + i * 16 + l15) * 32 + qe];
                bl[i] = *(const shortx8*)&v_l[s * 2048 + (wn + i * 16 + l15) * 32 + qe];
            }
#pragma unroll
            for (int i = 0; i < 2; i++)
#pragma unroll
                for (int j = 0; j < 2; j++) {
                    acc[i][j] = __builtin_amdgcn_mfma_f32_16x16x32_bf16(ah[i], bh[j], acc[i][j], 0, 0, 0);
                    acc[i][j] = __builtin_amdgcn_mfma_f32_16x16x32_bf16(al[i], bh[j], acc[i][j], 0, 0, 0);
                    acc[i][j] = __builtin_amdgcn_mfma_f32_16x16x32_bf16(ah[i], bl[j], acc[i][j], 0, 0, 0);
                }
        }
    }
#pragma unroll
    for (int j = 0; j < 2; j++) {
        const int col = h * 64 + wn + j * 16 + l15;
#pragma unroll
        for (int i = 0; i < 2; i++) {
#pragma unroll
            for (int r = 0; r < 4; r++) {
                const int row = qt * 64 + wm + i * 16 + l4 * 4 + r;
                obuf[(size_t)row * 2048 + col] = acc[i][j][r];
            }
        }
    }
}

// ---------------- exact quantile: radix select + candidate compaction ----------------
__global__ void sel_init_kernel(unsigned* __restrict__ sel, unsigned* __restrict__ hist,
                                unsigned kA, unsigned kB) {
    const int i = blockIdx.x * 256 + threadIdx.x;
    if (i < 4096) hist[i] = 0u;
    if (i == 0) { sel[0] = 0u; sel[1] = kA; sel[2] = 0u; sel[3] = kB; sel[4] = 0u; }
}

__global__ __launch_bounds__(256) void hist_pass_kernel(const float* __restrict__ vals, long n,
                                                        const unsigned* __restrict__ nptr, unsigned cap,
                                                        const unsigned* __restrict__ sel,
                                                        unsigned* __restrict__ hist,
                                                        int shift, unsigned prefmask) {
    __shared__ unsigned hloc[4096];
    for (int i = threadIdx.x; i < 4096; i += 256) hloc[i] = 0u;
    __syncthreads();
    if (nptr) { unsigned c = *nptr; n = (long)(c < cap ? c : cap); }
    const unsigned prefix = sel[0];
    const long stride = (long)gridDim.x * 256;
    unsigned zcnt = 0;
    for (long i = (long)blockIdx.x * 256 + threadIdx.x; i < n; i += stride) {
        const unsigned b = __float_as_uint(vals[i]);
        if ((b & prefmask) == prefix) {
            if (b == 0u) zcnt++;
            else atomicAdd(&hloc[(b >> shift) & 4095], 1u);
        }
    }
    if (zcnt) atomicAdd(&hloc[0], zcnt);
    __syncthreads();
    for (int i = threadIdx.x; i < 4096; i += 256) if (hloc[i]) atomicAdd(&hist[i], hloc[i]);
}

// block-aggregated compaction: LDS staging buffer, ONE global atomic per block
__global__ __launch_bounds__(256) void compact_kernel(const float* __restrict__ vals, long n,
                                                      const unsigned* __restrict__ selA,
                                                      const unsigned* __restrict__ selB,
                                                      float* __restrict__ cand,
                                                      unsigned* __restrict__ cnt, unsigned cap) {
    __shared__ float buf[4096];
    __shared__ unsigned lcnt, gbase;
    if (threadIdx.x == 0) lcnt = 0u;
    __syncthreads();
    const unsigned pa = selA[0], pb = selB[0];
    const long stride = (long)gridDim.x * 256;
    for (long i = (long)blockIdx.x * 256 + threadIdx.x; i < n; i += stride) {
        const float v = vals[i];
        const unsigned b = __float_as_uint(v);
        const unsigned hb = b & 0xFFF00000u;
        if (b != 0u && (hb == pa || hb == pb)) {
            const unsigned idx = atomicAdd(&lcnt, 1u);
            if (idx < 4096u) buf[idx] = v;
            else {   // rare overflow: direct append (exact count preserved)
                const unsigned g = atomicAdd(cnt, 1u);
                if (g < cap) cand[g] = v;
            }
        }
    }
    __syncthreads();
    if (threadIdx.x == 0) {
        const unsigned c = lcnt < 4096u ? lcnt : 4096u;
        gbase = atomicAdd(cnt, c);
    }
    __syncthreads();
    const unsigned c = lcnt < 4096u ? lcnt : 4096u;
    for (unsigned j = threadIdx.x; j < c; j += 256) {
        const unsigned idx = gbase + j;
        if (idx < cap) cand[idx] = buf[j];
    }
}

__global__ __launch_bounds__(256) void resolve_pass_kernel(unsigned* __restrict__ sel,
                                                           unsigned* __restrict__ hist,
                                                           int shift, int last,
                                                           float* __restrict__ res, int slot,
                                                           int clear) {
    __shared__ unsigned part[256];
    __shared__ unsigned bpos, boff;
    const int tid = threadIdx.x;
    if (tid == 0) { bpos = 4095u; boff = 0u; }
    unsigned vals[16]; unsigned s = 0;
#pragma unroll
    for (int i = 0; i < 16; i++) { vals[i] = hist[tid * 16 + i]; s += vals[i]; }
    part[tid] = s; __syncthreads();
    for (int off = 1; off < 256; off <<= 1) {
        unsigned v = (tid >= off) ? part[tid - off] : 0u;
        __syncthreads();
        part[tid] += v;
        __syncthreads();
    }
    const unsigned krem = sel[1];
    unsigned c = part[tid] - s;
#pragma unroll
    for (int i = 0; i < 16; i++) {
        if (krem >= c && krem < c + vals[i]) { bpos = tid * 16 + i; boff = krem - c; }
        c += vals[i];
    }
    __syncthreads();
    if (tid == 0) {
        const unsigned p = sel[0] | (bpos << shift);
        sel[0] = p; sel[1] = boff;
        if (last) res[slot] = __uint_as_float(p);
    }
    if (clear) for (int i = 0; i < 16; i++) hist[tid * 16 + i] = 0u;
}

__global__ void finalize_thr_kernel(const float* __restrict__ res, float* __restrict__ out) {
    if (threadIdx.x == 0) out[0] = res[0] + (res[1] - res[0]) * 0.45f;
}

// ---------------- host side ----------------
extern "C" void kernel_launch(void* const* d_in, const int* in_sizes, int n_in,
                              void* d_out, int out_size, void* d_ws, size_t ws_size,
                              hipStream_t stream) {
    (void)in_sizes; (void)n_in; (void)out_size; (void)ws_size;
    const float* x    = (const float*)d_in[0];
    const float* w1   = (const float*)d_in[1];
    const float* w2   = (const float*)d_in[2];
    const float* cosp = (const float*)d_in[3];
    const float* sinp = (const float*)d_in[4];
    const int*   wi_q = (const int*)d_in[6];
    const float* sc_q = (const float*)d_in[7];
    const float* b_q  = (const float*)d_in[8];
    const float* la_q = (const float*)d_in[9];
    const float* lb_q = (const float*)d_in[10];
    const int*   wi_k = (const int*)d_in[11];
    const float* sc_k = (const float*)d_in[12];
    const float* b_k  = (const float*)d_in[13];
    const float* la_k = (const float*)d_in[14];
    const float* lb_k = (const float*)d_in[15];
    const int*   wi_v = (const int*)d_in[16];
    const float* sc_v = (const float*)d_in[17];
    const float* b_v  = (const float*)d_in[18];
    const float* la_v = (const float*)d_in[19];
    const float* lb_v = (const float*)d_in[20];
    const int*   wi_o = (const int*)d_in[21];
    const float* sc_o = (const float*)d_in[22];
    const float* b_o  = (const float*)d_in[23];
    const float* la_o = (const float*)d_in[24];
    const float* lb_o = (const float*)d_in[25];
    const int*   wi_g = (const int*)d_in[26];
    const float* sc_g = (const float*)d_in[27];
    const float* b_g  = (const float*)d_in[28];
    const float* la_g = (const float*)d_in[29];
    const float* lb_g = (const float*)d_in[30];
    const int*   wi_u = (const int*)d_in[31];
    const float* sc_u = (const float*)d_in[32];
    const float* b_u  = (const float*)d_in[33];
    const float* la_u = (const float*)d_in[34];
    const float* lb_u = (const float*)d_in[35];
    const int*   wi_d = (const int*)d_in[36];
    const float* sc_d = (const float*)d_in[37];
    const float* b_d  = (const float*)d_in[38];
    const float* la_d = (const float*)d_in[39];
    const float* lb_d = (const float*)d_in[40];

    float* F    = (float*)d_ws;
    float* XN1  = F + WS_XN1;
    float* Q    = F + WS_Q;
    float* K    = F + WS_KB;
    float* V    = F + WS_VB;
    float* O    = F + WS_OB;
    float* XMED = F + WS_XMED;
    float* XN2  = F + WS_XN2;
    float* PROBS= F + WS_PROBS;
    float* GATE = F + B_GATE;
    float* UP   = F + B_UP;
    float* HAD  = F + B_HAD;
    float* CAND = F + CAND_OFF;
    float* XA32 = F + XA32_OFF;
    unsigned* CMX   = (unsigned*)(F + CM_X);
    unsigned* CMXN1 = (unsigned*)(F + CM_XN1);
    unsigned* CMQ   = (unsigned*)(F + CM_Qb);
    unsigned* CMK   = (unsigned*)(F + CM_Kb);
    unsigned* CMV   = (unsigned*)(F + CM_Vb);
    unsigned* CMO   = (unsigned*)(F + CM_Ob);
    unsigned* CMXM  = (unsigned*)(F + CM_XM);
    unsigned* CMXN2 = (unsigned*)(F + CM_XN2b);
    unsigned* CMG   = (unsigned*)(F + CM_GATE);
    unsigned* CMF   = (unsigned*)(F + CM_FN);
    unsigned* CMU   = (unsigned*)(F + CM_UPb);
    unsigned* CMH   = (unsigned*)(F + CM_HAD);
    int*      IDX0  = (int*)(F + WS_IDX);
    int*      IDX1  = IDX0 + 20;
    unsigned* HIST  = (unsigned*)(F + WS_HIST);
    unsigned* SEL   = (unsigned*)(F + WS_SEL);
    float*    RES   = F + WS_RES;
    float*    OUT   = (float*)d_out;
    #define US(off) ((unsigned short*)(F + (off)))

    // 0. zero column-max accumulators
    zero_kernel<<<(CM_TOTAL + 255) / 256, 256, 0, stream>>>(CMX, CM_TOTAL);

    // 1. rmsnorm1 + x channel pack; weights q/k/v -> bf16 (phase A)
    rmsnorm_kernel<<<1024, 256, 0, stream>>>(x, w1, XN1);
    colabsmax_kernel<<<dim3(8, 64), 256, 0, stream>>>(x, 1024, 2048, CMX);
    topk20_kernel<<<1, 256, 0, stream>>>(CMX, OUT + O_XIDX, IDX0);
    packscale_kernel<<<8, 256, 0, stream>>>(CMX, IDX0, OUT + O_XSC, 2048);
    colabsmax_kernel<<<dim3(8, 64), 256, 0, stream>>>(XN1, 1024, 2048, CMXN1);
    w2bf_kernel<<<4096, 256, 0, stream>>>(wi_q, US(A_WQ), 1048576);
    w2bf_kernel<<<1024, 256, 0, stream>>>(wi_k, US(A_WK), 262144);
    w2bf_kernel<<<1024, 256, 0, stream>>>(wi_v, US(A_WV), 262144);

    // 2. q/k/v fused split-K MFMA GEMM (XA32 lives in WS_Q; GEMM overwrites Q afterwards)
    hilo_kernel<<<2048, 256, 0, stream>>>(XN1, US(A_XN1H), US(A_XN1L), 524288);
    zero_kernel<<<192, 256, 0, stream>>>((unsigned*)XA32, 49152);
    lora_xa2_kernel<<<dim3(1024, 4, 3), 256, 0, stream>>>(XN1, 2048, la_q, la_k, la_v, XA32);
    xa_cvt_kernel<<<dim3(128, 3), 256, 0, stream>>>(XA32,
        US(A_XAQH), US(A_XAQL), US(A_XAKH), US(A_XAKL), US(A_XAVH), US(A_XAVL));
    lbt_kernel<<<8, 256, 0, stream>>>(lb_q, sc_q, US(A_LBTQ), 2048);
    lbt_kernel<<<2, 256, 0, stream>>>(lb_k, sc_k, US(A_LBTK), 512);
    lbt_kernel<<<2, 256, 0, stream>>>(lb_v, sc_v, US(A_LBTV), 512);
    zero_kernel<<<12288, 256, 0, stream>>>((unsigned*)Q, 3145728);   // Q,K,V contiguous
    {
        Seg sq{US(A_WQ), US(A_XAQH), US(A_XAQL), US(A_LBTQ), sc_q, b_q, nullptr, Q, 2048, 0};
        Seg sk{US(A_WK), US(A_XAKH), US(A_XAKL), US(A_LBTK), sc_k, b_k, nullptr, K, 512, 16};
        Seg sv{US(A_WV), US(A_XAVH), US(A_XAVL), US(A_LBTV), sc_v, b_v, nullptr, V, 512, 20};
        gemm_mfma3_kernel<<<dim3(24, 8, 2), 256, 0, stream>>>(US(A_XN1H), US(A_XN1L), 2048, 1024, 2, 16, 20, sq, sk, sv);
    }

    // 3. rope (emits bf16 hi/lo) + scales + V transpose
    rope_kernel<<<4096, 256, 0, stream>>>(Q, US(AT_QHG), US(AT_QLG), cosp, sinp, 32);
    rope_kernel<<<1024, 256, 0, stream>>>(K, US(AT_KHG), US(AT_KLG), cosp, sinp, 8);
    colabsmax_kernel<<<dim3(1, 256), 256, 0, stream>>>(Q, 32768, 64, CMQ);
    colabsmax_kernel<<<dim3(1, 128), 256, 0, stream>>>(K, 8192, 64, CMK);
    vtrans_kernel<<<dim3(16, 8), 256, 0, stream>>>(V, US(AT_VTH), US(AT_VTL), CMV);

    // 4. attention (MFMA)
    score_mfma_kernel<<<dim3(36, 32), 256, 0, stream>>>(US(AT_QHG), US(AT_QLG), US(AT_KHG), US(AT_KLG), PROBS);
    softmax_kernel<<<32768, 256, 0, stream>>>(PROBS);
    av_mfma_kernel<<<dim3(16, 32), 256, 0, stream>>>(PROBS, US(AT_VTH), US(AT_VTL), O);
    colabsmax_kernel<<<dim3(8, 64), 256, 0, stream>>>(O, 1024, 2048, CMO);

    // 5. a_thr: ranks 31876709/31876710 of 33554432, frac 0.45
    const long NP = 33554432L;
    sel_init_kernel<<<16, 256, 0, stream>>>(SEL, HIST, 31876709u, 31876710u);
    hist_pass_kernel<<<4096, 256, 0, stream>>>(PROBS, NP, nullptr, 0, SEL + 0, HIST, 20, 0x00000000u);
    resolve_pass_kernel<<<1, 256, 0, stream>>>(SEL + 0, HIST, 20, 0, RES, 0, 0);
    resolve_pass_kernel<<<1, 256, 0, stream>>>(SEL + 2, HIST, 20, 0, RES, 1, 1);
    compact_kernel<<<4096, 256, 0, stream>>>(PROBS, NP, SEL + 0, SEL + 2, CAND, SEL + 4, CAP_CAND);
    hist_pass_kernel<<<256, 256, 0, stream>>>(CAND, 0, SEL + 4, CAP_CAND, SEL + 0, HIST, 8, 0xFFF00000u);
    resolve_pass_kernel<<<1, 256, 0, stream>>>(SEL + 0, HIST, 8, 0, RES, 0, 1);
    hist_pass_kernel<<<256, 256, 0, stream>>>(CAND, 0, SEL + 4, CAP_CAND, SEL + 2, HIST, 8, 0xFFF00000u);
    resolve_pass_kernel<<<1, 256, 0, stream>>>(SEL + 2, HIST, 8, 0, RES, 1, 1);
    hist_pass_kernel<<<256, 256, 0, stream>>>(CAND, 0, SEL + 4, CAP_CAND, SEL + 0, HIST, 0, 0xFFFFFF00u);
    resolve_pass_kernel<<<1, 256, 0, stream>>>(SEL + 0, HIST, 0, 1, RES, 0, 1);
    hist_pass_kernel<<<256, 256, 0, stream>>>(CAND, 0, SEL + 4, CAP_CAND, SEL + 2, HIST, 0, 0xFFFFFF00u);
    resolve_pass_kernel<<<1, 256, 0, stream>>>(SEL + 2, HIST, 0, 1, RES, 1, 1);
    finalize_thr_kernel<<<1, 64, 0, stream>>>(RES, OUT + O_ATHR);

    // 6. o projection (split-K x4, +residual x) -> x_med; pack; rmsnorm2
    w2bf_kernel<<<4096, 256, 0, stream>>>(wi_o, US(B_WO), 1048576);
    hilo_kernel<<<2048, 256, 0, stream>>>(O, US(B_OH), US(B_OL), 524288);
    zero_kernel<<<64, 256, 0, stream>>>((unsigned*)XA32, 16384);
    lora_xa2_kernel<<<dim3(1024, 4, 1), 256, 0, stream>>>(O, 2048, la_o, la_o, la_o, XA32);
    xa_cvt_kernel<<<dim3(128, 1), 256, 0, stream>>>(XA32,
        US(B_XAOH), US(B_XAOL), US(B_XAOH), US(B_XAOL), US(B_XAOH), US(B_XAOL));
    lbt_kernel<<<8, 256, 0, stream>>>(lb_o, sc_o, US(B_LBTO), 2048);
    zero_kernel<<<8192, 256, 0, stream>>>((unsigned*)XMED, 2097152);
    {
        Seg so{US(B_WO), US(B_XAOH), US(B_XAOL), US(B_LBTO), sc_o, b_o, x, XMED, 2048, 0};
        gemm_mfma3_kernel<<<dim3(16, 8, 4), 256, 0, stream>>>(US(B_OH), US(B_OL), 2048, 512, 4, 999, 999, so, so, so);
    }
    colabsmax_kernel<<<dim3(8, 64), 256, 0, stream>>>(XMED, 1024, 2048, CMXM);
    topk20_kernel<<<1, 256, 0, stream>>>(CMXM, OUT + O_XMIDX, IDX1);
    packscale_kernel<<<8, 256, 0, stream>>>(CMXM, IDX1, OUT + O_XMS, 2048);
    rmsnorm_kernel<<<1024, 256, 0, stream>>>(XMED, w2, XN2);
    colabsmax_kernel<<<dim3(8, 64), 256, 0, stream>>>(XN2, 1024, 2048, CMXN2);

    // 7. MLP: gate+up fused GEMM, fused silu/hadamard + 4 col-maxes
    w2bf_kernel<<<11264, 256, 0, stream>>>(wi_g, US(B_WG), 2883584);
    w2bf_kernel<<<11264, 256, 0, stream>>>(wi_u, US(B_WU), 2883584);
    hilo_kernel<<<2048, 256, 0, stream>>>(XN2, US(B_XN2H), US(B_XN2L), 524288);
    zero_kernel<<<128, 256, 0, stream>>>((unsigned*)XA32, 32768);
    lora_xa2_kernel<<<dim3(1024, 4, 2), 256, 0, stream>>>(XN2, 2048, la_g, la_u, la_u, XA32);
    xa_cvt_kernel<<<dim3(128, 2), 256, 0, stream>>>(XA32,
        US(B_XAGH), US(B_XAGL), US(B_XAUH), US(B_XAUL), US(B_XAUH), US(B_XAUL));
    lbt_kernel<<<22, 256, 0, stream>>>(lb_g, sc_g, US(B_LBTG), 5632);
    lbt_kernel<<<22, 256, 0, stream>>>(lb_u, sc_u, US(B_LBTU), 5632);
    {
        Seg sg{US(B_WG), US(B_XAGH), US(B_XAGL), US(B_LBTG), sc_g, b_g, nullptr, GATE, 5632, 0};
        Seg su{US(B_WU), US(B_XAUH), US(B_XAUL), US(B_LBTU), sc_u, b_u, nullptr, UP, 5632, 44};
        gemm_mfma3_kernel<<<dim3(88, 8, 1), 256, 0, stream>>>(US(B_XN2H), US(B_XN2L), 2048, 2048, 1, 44, 88, sg, su, su);
    }
    w2bf_kernel<<<11264, 256, 0, stream>>>(wi_d, US(B_WD), 2883584);
    hadfuse_kernel<<<dim3(22, 32), 256, 0, stream>>>(GATE, UP, HAD, CMG, CMF, CMU, CMH);

    // 8. down projection (split-K x4, +residual x_med) -> x_out
    hilo_kernel<<<5632, 256, 0, stream>>>(HAD, US(B_HADH), US(B_HADL), 1441792);
    zero_kernel<<<64, 256, 0, stream>>>((unsigned*)XA32, 16384);
    lora_xa2_kernel<<<dim3(1024, 11, 1), 256, 0, stream>>>(HAD, 5632, la_d, la_d, la_d, XA32);
    xa_cvt_kernel<<<dim3(128, 1), 256, 0, stream>>>(XA32,
        US(B_XADH), US(B_XADL), US(B_XADH), US(B_XADL), US(B_XADH), US(B_XADL));
    lbt_kernel<<<8, 256, 0, stream>>>(lb_d, sc_d, US(B_LBTD), 2048);
    zero_kernel<<<8192, 256, 0, stream>>>((unsigned*)(OUT + O_XOUT), 2097152);
    {
        Seg sd{US(B_WD), US(B_XADH), US(B_XADL), US(B_LBTD), sc_d, b_d, XMED, OUT + O_XOUT, 2048, 0};
        gemm_mfma3_kernel<<<dim3(16, 8, 4), 256, 0, stream>>>(US(B_HADH), US(B_HADL), 5632, 1408, 4, 999, 999, sd, sd, sd);
    }

    // 9. all act_quant scales in one pass
    scale_fin_all_kernel<<<113, 256, 0, stream>>>((const unsigned*)(F + WS_SMALL), OUT);
    #undef US
}